// Round 13
// baseline (434.330 us; speedup 1.0000x reference)
//
#include <hip/hip_runtime.h>
#include <hip/hip_fp16.h>
#include <math.h>

#define EPSBN 1e-5f
#define NBMAX 2048          // max buckets (256 rows each) for radix path
#define TPT 32              // entries per thread in passA/bhist
#define CAPB 8192           // passB2 LDS staging capacity (entries)

typedef int int4v __attribute__((ext_vector_type(4)));

__device__ __forceinline__ float elu1(float x) { return x > 0.f ? x : expm1f(x); }

// dot of 8 half pairs (packed in float4 bit patterns), fp32 accumulate
__device__ __forceinline__ float dot8h(float4 hv, float4 wv, float acc) {
#if defined(__has_builtin)
#if __has_builtin(__builtin_amdgcn_fdot2)
    typedef _Float16 h2v __attribute__((ext_vector_type(2)));
    union { float4 f; h2v h[4]; } a, b;
    a.f = hv; b.f = wv;
#pragma unroll
    for (int i = 0; i < 4; ++i)
        acc = __builtin_amdgcn_fdot2(a.h[i], b.h[i], acc, false);
    return acc;
#endif
#endif
    const __half2* ha = (const __half2*)&hv;
    const __half2* wa = (const __half2*)&wv;
#pragma unroll
    for (int i = 0; i < 4; ++i) {
        float2 hf = __half22float2(ha[i]);
        float2 wf = __half22float2(wa[i]);
        acc = fmaf(hf.x, wf.x, acc);
        acc = fmaf(hf.y, wf.y, acc);
    }
    return acc;
}

// ============================================================================
// Radix path: bucket histogram (LDS, vectorized reads) + tiny scan (+cursor init)
// ============================================================================

__global__ void bhist_lds(const int* __restrict__ out_idx, int* __restrict__ bcnt, int M, int NB) {
    __shared__ int hcnt[NBMAX];
    for (int t = threadIdx.x; t < NB; t += 256) hcnt[t] = 0;
    __syncthreads();
    int k = blockIdx.y;
    const size_t koff = (size_t)k * M;
    int base = blockIdx.x * (256 * TPT);
    bool vec = (M & 3) == 0;
#pragma unroll
    for (int jj = 0; jj < TPT / 4; ++jj) {
        int m0 = base + (jj * 256 + (int)threadIdx.x) * 4;
        if (vec && m0 + 3 < M) {
            int4v v = *(const int4v*)(out_idx + koff + m0);
            atomicAdd(&hcnt[(unsigned)v.x >> 8], 1);
            atomicAdd(&hcnt[(unsigned)v.y >> 8], 1);
            atomicAdd(&hcnt[(unsigned)v.z >> 8], 1);
            atomicAdd(&hcnt[(unsigned)v.w >> 8], 1);
        } else {
            for (int q = 0; q < 4; ++q) {
                int m = m0 + q;
                if (m < M) atomicAdd(&hcnt[out_idx[koff + m] >> 8], 1);
            }
        }
    }
    __syncthreads();
    for (int t = threadIdx.x; t < NB; t += 256) {
        int c = hcnt[t];
        if (c) atomicAdd(&bcnt[t], c);
    }
}

// single block: exclusive scan of bucket counts -> bbase[0..NB] + padded cursors
__global__ void bscan(const int* __restrict__ bcnt, int* __restrict__ bbase,
                      int* __restrict__ bcur, int NB, int E) {
    __shared__ int tmp[256];
    int carry = 0;
    for (int base = 0; base < NB; base += 256) {
        int i = base + threadIdx.x;
        int v = (i < NB) ? bcnt[i] : 0;
        tmp[threadIdx.x] = v;
        __syncthreads();
        for (int off = 1; off < 256; off <<= 1) {
            int t = (threadIdx.x >= off) ? tmp[threadIdx.x - off] : 0;
            __syncthreads();
            tmp[threadIdx.x] += t;
            __syncthreads();
        }
        if (i < NB) {
            int ex = tmp[threadIdx.x] - v + carry;
            bbase[i] = ex;
            bcur[i * 16] = ex;
        }
        carry += tmp[255];
        __syncthreads();
    }
    if (threadIdx.x == 0) bbase[NB] = E;
}

// ============================================================================
// passA: bucket scatter (vectorized reads). tmp[pos] = (out&255)<<24|k<<19|in
// ============================================================================

__global__ void passA(const int* __restrict__ in_idx, const int* __restrict__ out_idx,
                      int* __restrict__ bcur, unsigned* __restrict__ tmp, int M, int NB) {
    __shared__ int cnt[NBMAX];
    __shared__ int gbase[NBMAX];
    for (int t = threadIdx.x; t < NB; t += 256) cnt[t] = 0;
    __syncthreads();
    int k = blockIdx.y;
    const size_t koff = (size_t)k * M;
    int base = blockIdx.x * (256 * TPT);
    unsigned pk[TPT];
    int bk[TPT];
    bool vec = (M & 3) == 0;
#pragma unroll
    for (int jj = 0; jj < TPT / 4; ++jj) {
        int m0 = base + (jj * 256 + (int)threadIdx.x) * 4;
        if (vec && m0 + 3 < M) {
            int4v vi = *(const int4v*)(in_idx + koff + m0);
            int4v vo = *(const int4v*)(out_idx + koff + m0);
#pragma unroll
            for (int q = 0; q < 4; ++q) {
                unsigned in = (unsigned)vi[q];
                unsigned out = (unsigned)vo[q];
                pk[jj * 4 + q] = ((out & 255u) << 24) | ((unsigned)k << 19) | in;
                bk[jj * 4 + q] = (int)(out >> 8);
                atomicAdd(&cnt[bk[jj * 4 + q]], 1);
            }
        } else {
#pragma unroll
            for (int q = 0; q < 4; ++q) {
                int m = m0 + q;
                if (m < M) {
                    unsigned in = (unsigned)in_idx[koff + m];
                    unsigned out = (unsigned)out_idx[koff + m];
                    pk[jj * 4 + q] = ((out & 255u) << 24) | ((unsigned)k << 19) | in;
                    bk[jj * 4 + q] = (int)(out >> 8);
                    atomicAdd(&cnt[bk[jj * 4 + q]], 1);
                } else bk[jj * 4 + q] = -1;
            }
        }
    }
    __syncthreads();
    for (int b = threadIdx.x; b < NB; b += 256) {
        int c = cnt[b];
        gbase[b] = c ? atomicAdd(&bcur[b * 16], c) : 0;
        cnt[b] = 0;   // reuse as local slot cursor
    }
    __syncthreads();
#pragma unroll
    for (int j = 0; j < TPT; ++j) {
        if (bk[j] >= 0) {
            int slot = atomicAdd(&cnt[bk[j]], 1);
            tmp[gbase[bk[j]] + slot] = pk[j];
        }
    }
}

// ============================================================================
// passB2: per bucket — row counting-sort (LDS), write entries + offsets,
// and FUSED stage-1: one thread per row computes h from LDS-resident entries.
// ============================================================================

__global__ void passB2(const unsigned* __restrict__ tmp, const int* __restrict__ bbase,
                       unsigned* __restrict__ entries, int* __restrict__ offsets,
                       const float* __restrict__ x, const float* __restrict__ W1,
                       const float* __restrict__ g1, const float* __restrict__ b1,
                       const float* __restrict__ m1, const float* __restrict__ v1,
                       __half* __restrict__ h, int N, int K, int E, int NB) {
    __shared__ unsigned stg[CAPB];
    __shared__ int rcnt[256], rbase[256], rcur[256], sc[256];
    __shared__ float w1s[32 * 16];
    __shared__ float scb[16], bib[16];
    int b = blockIdx.x;
    int r0 = b << 8;
    int nr = N - r0; if (nr > 256) nr = 256;
    int gbeg = bbase[b], gend = bbase[b + 1];
    int count = gend - gbeg;
    for (int t = threadIdx.x; t < K * 16; t += 256) w1s[t] = W1[t];
    if (threadIdx.x < 16) {
        float scale = g1[threadIdx.x] * rsqrtf(v1[threadIdx.x] + EPSBN);
        scb[threadIdx.x] = scale;
        bib[threadIdx.x] = b1[threadIdx.x] - m1[threadIdx.x] * scale;
    }
    rcnt[threadIdx.x] = 0;
    __syncthreads();
    for (int i = threadIdx.x; i < count; i += 256)
        atomicAdd(&rcnt[tmp[gbeg + i] >> 24], 1);
    __syncthreads();
    int v = rcnt[threadIdx.x];
    sc[threadIdx.x] = v;
    __syncthreads();
    for (int off = 1; off < 256; off <<= 1) {
        int t = (threadIdx.x >= off) ? sc[threadIdx.x - off] : 0;
        __syncthreads();
        sc[threadIdx.x] += t;
        __syncthreads();
    }
    rbase[threadIdx.x] = sc[threadIdx.x] - v;
    rcur[threadIdx.x] = sc[threadIdx.x] - v;
    if (threadIdx.x < nr) offsets[r0 + threadIdx.x] = gbeg + rbase[threadIdx.x];
    if (b == NB - 1 && threadIdx.x == 0) offsets[N] = E;
    __syncthreads();

    if (count <= CAPB) {
        for (int i = threadIdx.x; i < count; i += 256) {
            unsigned vv = tmp[gbeg + i];
            int slot = atomicAdd(&rcur[vv >> 24], 1);
            stg[slot] = vv & 0x00FFFFFFu;
        }
        __syncthreads();
        for (int i = threadIdx.x; i < count; i += 256)
            entries[gbeg + i] = stg[i];
        if (threadIdx.x < nr) {
            float acc[16];
#pragma unroll
            for (int c = 0; c < 16; ++c) acc[c] = 0.f;
            int rb = rbase[threadIdx.x], re = rb + rcnt[threadIdx.x];
            for (int i = rb; i < re; ++i) {
                unsigned vv = stg[i];
                float xv = x[vv & 0x7FFFFu];
                const float* wr = &w1s[((vv >> 19) & 31) << 4];
#pragma unroll
                for (int c = 0; c < 16; ++c) acc[c] = fmaf(xv, wr[c], acc[c]);
            }
            int row = r0 + threadIdx.x;
            float4 pack[2];
            __half2* hp = (__half2*)pack;
#pragma unroll
            for (int q = 0; q < 8; ++q) {
                __half2 hh;
                hh.x = __float2half(elu1(acc[2 * q] * scb[2 * q] + bib[2 * q]));
                hh.y = __float2half(elu1(acc[2 * q + 1] * scb[2 * q + 1] + bib[2 * q + 1]));
                hp[q] = hh;
            }
            float4* dst = (float4*)(h + (size_t)row * 16);
            dst[0] = pack[0];
            dst[1] = pack[1];
        }
    } else {
        for (int i = threadIdx.x; i < count; i += 256) {
            unsigned vv = tmp[gbeg + i];
            int slot = atomicAdd(&rcur[vv >> 24], 1);
            entries[gbeg + slot] = vv & 0x00FFFFFFu;
        }
        __syncthreads();
        if (threadIdx.x < nr) {
            float acc[16];
#pragma unroll
            for (int c = 0; c < 16; ++c) acc[c] = 0.f;
            int rb = rbase[threadIdx.x], re = rb + rcnt[threadIdx.x];
            for (int i = rb; i < re; ++i) {
                unsigned vv = entries[gbeg + i];
                float xv = x[vv & 0x7FFFFu];
                const float* wr = &w1s[((vv >> 19) & 31) << 4];
#pragma unroll
                for (int c = 0; c < 16; ++c) acc[c] = fmaf(xv, wr[c], acc[c]);
            }
            int row = r0 + threadIdx.x;
            float4 pack[2];
            __half2* hp = (__half2*)pack;
#pragma unroll
            for (int q = 0; q < 8; ++q) {
                __half2 hh;
                hh.x = __float2half(elu1(acc[2 * q] * scb[2 * q] + bib[2 * q]));
                hh.y = __float2half(elu1(acc[2 * q + 1] * scb[2 * q + 1] + bib[2 * q + 1]));
                hp[q] = hh;
            }
            float4* dst = (float4*)(h + (size_t)row * 16);
            dst[0] = pack[0];
            dst[1] = pack[1];
        }
    }
}

// W2T[k][d][c] = (half)W2[k][c][d]  (27 KB)
__global__ void transpose_W2(const float* __restrict__ W2, __half* __restrict__ W2T, int total) {
    int i = blockIdx.x * 256 + threadIdx.x;
    if (i >= total) return;
    int k = i >> 9;
    int r = i & 511;
    int c = r >> 5, d = r & 31;
    W2T[(k << 9) | (d << 4) | c] = __float2half(W2[i]);
}

// ============================================================================
// Stage 2 gather v3: weights in LDS (padded rows: 20 halves -> bank-friendly
// b64 reads), 1024-thread blocks (32 half-waves) for 100% occupancy.
// Cooperative lane-per-entry h staging unchanged from v2.
// ============================================================================

__global__ __launch_bounds__(1024) void s2_gather_v3(
        const __half* __restrict__ h, const __half* __restrict__ W2T,
        const float* __restrict__ g2, const float* __restrict__ b2,
        const float* __restrict__ m2, const float* __restrict__ v2,
        const int* __restrict__ offsets, const unsigned* __restrict__ entries,
        float* __restrict__ out, int N, int K, int shift, unsigned mask) {
    __shared__ __half stg[32][32 * 16 + 8];
    __shared__ __half w2ls[32 * 640];          // k*640 + d*20 + c  (pad 16->20)
    for (int t = threadIdx.x; t < K * 512; t += 1024) {
        int k = t >> 9, r = t & 511;           // r = d*16 + c
        w2ls[k * 640 + (r >> 4) * 20 + (r & 15)] = W2T[t];
    }
    __syncthreads();
    int hw = threadIdx.x >> 5;
    int lane = threadIdx.x & 31;
    int row = blockIdx.x * 32 + hw;
    if (row < N) {
        int d = lane;
        int beg = offsets[row], end = offsets[row + 1];
        float acc = 0.f;
        __half* my = stg[hw];
        for (int base = beg; base < end; base += 32) {
            int cnt = end - base; if (cnt > 32) cnt = 32;
            unsigned ev = entries[base + (lane < cnt ? lane : cnt - 1)];
            if (lane < cnt) {
                const float4* hp = (const float4*)(h + ((size_t)(ev & mask) << 4));
                float4 h0 = hp[0], h1 = hp[1];
                float4* dst = (float4*)(my + lane * 16);
                dst[0] = h0;
                dst[1] = h1;
            }
            asm volatile("s_waitcnt lgkmcnt(0)" ::: "memory");
            for (int j = 0; j < cnt; ++j) {
                unsigned pk0 = __shfl(ev, j, 32);
                const float4* hr0 = (const float4*)(my + j * 16);
                float4 ha0 = hr0[0], hb0 = hr0[1];
                const float2* wp = (const float2*)(w2ls + (size_t)(pk0 >> shift) * 640 + (unsigned)d * 20);
                float2 wa = wp[0], wb = wp[1], wc = wp[2], wd = wp[3];
                float4 w0; w0.x = wa.x; w0.y = wa.y; w0.z = wb.x; w0.w = wb.y;
                float4 w1; w1.x = wc.x; w1.y = wc.y; w1.z = wd.x; w1.w = wd.y;
                acc = dot8h(ha0, w0, acc);
                acc = dot8h(hb0, w1, acc);
            }
            asm volatile("s_waitcnt lgkmcnt(0)" ::: "memory");
        }
        float scale = g2[d] * rsqrtf(v2[d] + EPSBN);
        float bias = b2[d] - m2[d] * scale;
        out[(size_t)row * 32 + d] = elu1(acc * scale + bias);
    }
}

// v2 retained for the K>32 CSR path
__global__ void s2_gather_v2(const __half* __restrict__ h, const __half* __restrict__ W2T,
                             const float* __restrict__ g2, const float* __restrict__ b2,
                             const float* __restrict__ m2, const float* __restrict__ v2,
                             const int* __restrict__ offsets, const unsigned* __restrict__ entries,
                             float* __restrict__ out, int N, int shift, unsigned mask) {
    __shared__ __half stg[8][32 * 16 + 8];
    int hw = threadIdx.x >> 5;
    int lane = threadIdx.x & 31;
    int row = blockIdx.x * 8 + hw;
    if (row >= N) return;
    int d = lane;
    int beg = offsets[row], end = offsets[row + 1];
    float acc = 0.f;
    __half* my = stg[hw];
    for (int base = beg; base < end; base += 32) {
        int cnt = end - base; if (cnt > 32) cnt = 32;
        unsigned ev = entries[base + (lane < cnt ? lane : cnt - 1)];
        if (lane < cnt) {
            const float4* hp = (const float4*)(h + ((size_t)(ev & mask) << 4));
            float4 h0 = hp[0], h1 = hp[1];
            float4* dst = (float4*)(my + lane * 16);
            dst[0] = h0;
            dst[1] = h1;
        }
        asm volatile("s_waitcnt lgkmcnt(0)" ::: "memory");
        for (int j = 0; j < cnt; ++j) {
            unsigned pk0 = __shfl(ev, j, 32);
            const float4* hr0 = (const float4*)(my + j * 16);
            float4 ha0 = hr0[0], hb0 = hr0[1];
            const float4* wp0 = (const float4*)(W2T + (((size_t)(pk0 >> shift) << 9) | ((unsigned)d << 4)));
            acc = dot8h(ha0, wp0[0], acc);
            acc = dot8h(hb0, wp0[1], acc);
        }
        asm volatile("s_waitcnt lgkmcnt(0)" ::: "memory");
    }
    float scale = g2[d] * rsqrtf(v2[d] + EPSBN);
    float bias = b2[d] - m2[d] * scale;
    out[(size_t)row * 32 + d] = elu1(acc * scale + bias);
}

// ============================================================================
// Non-radix CSR fallback kernels
// ============================================================================

__global__ void hist_kernel(const int* __restrict__ out_idx, int* __restrict__ cnt, int M) {
    int m = (blockIdx.x * blockDim.x + threadIdx.x) * 4;
    if (m >= M) return;
    size_t e = (size_t)blockIdx.y * M + m;
    if (m + 3 < M && ((M & 3) == 0)) {
        int4v v = *(const int4v*)(out_idx + e);
        atomicAdd(&cnt[v.x], 1);
        atomicAdd(&cnt[v.y], 1);
        atomicAdd(&cnt[v.z], 1);
        atomicAdd(&cnt[v.w], 1);
    } else {
        for (int j = 0; j < M - m && j < 4; ++j) atomicAdd(&cnt[out_idx[e + j]], 1);
    }
}

__global__ void scan_block_sums(const int* __restrict__ cnt, int* __restrict__ bsum, int N) {
    __shared__ int tmp[256];
    int i = blockIdx.x * 256 + threadIdx.x;
    tmp[threadIdx.x] = (i < N) ? cnt[i] : 0;
    __syncthreads();
    for (int off = 128; off > 0; off >>= 1) {
        if (threadIdx.x < off) tmp[threadIdx.x] += tmp[threadIdx.x + off];
        __syncthreads();
    }
    if (threadIdx.x == 0) bsum[blockIdx.x] = tmp[0];
}

__global__ void scan_bsums(int* __restrict__ bsum, int nb, int* __restrict__ offsets, int N, int E) {
    __shared__ int tmp[256];
    int carry = 0;
    for (int base = 0; base < nb; base += 256) {
        int i = base + threadIdx.x;
        int v = (i < nb) ? bsum[i] : 0;
        tmp[threadIdx.x] = v;
        __syncthreads();
        for (int off = 1; off < 256; off <<= 1) {
            int t = (threadIdx.x >= off) ? tmp[threadIdx.x - off] : 0;
            __syncthreads();
            tmp[threadIdx.x] += t;
            __syncthreads();
        }
        int incl = tmp[threadIdx.x];
        int total = tmp[255];
        if (i < nb) bsum[i] = incl - v + carry;
        carry += total;
        __syncthreads();
    }
    if (threadIdx.x == 0) offsets[N] = E;
}

__global__ void scan_final(const int* __restrict__ cnt, const int* __restrict__ bsum,
                           int* __restrict__ offsets, int* __restrict__ cursor, int N) {
    __shared__ int tmp[256];
    int i = blockIdx.x * 256 + threadIdx.x;
    int v = (i < N) ? cnt[i] : 0;
    tmp[threadIdx.x] = v;
    __syncthreads();
    for (int off = 1; off < 256; off <<= 1) {
        int t = (threadIdx.x >= off) ? tmp[threadIdx.x - off] : 0;
        __syncthreads();
        tmp[threadIdx.x] += t;
        __syncthreads();
    }
    if (i < N) {
        int o = tmp[threadIdx.x] - v + bsum[blockIdx.x];
        offsets[i] = o;
        cursor[i] = o;
    }
}

__global__ void scatter_entries(const int* __restrict__ in_idx, const int* __restrict__ out_idx,
                                int* __restrict__ cursor, unsigned* __restrict__ entries, int M, int shift) {
    int m = blockIdx.x * blockDim.x + threadIdx.x;
    if (m >= M) return;
    int k = blockIdx.y;
    size_t e = (size_t)k * M + m;
    int pos = atomicAdd(&cursor[out_idx[e]], 1);
    entries[pos] = (unsigned)in_idx[e] | ((unsigned)k << shift);
}

__global__ void s1_gather_v2(const float* __restrict__ x, const float* __restrict__ W1,
                             const float* __restrict__ g1, const float* __restrict__ b1,
                             const float* __restrict__ m1, const float* __restrict__ v1,
                             const int* __restrict__ offsets, const unsigned* __restrict__ entries,
                             __half* __restrict__ h, int N, int K, int shift, unsigned mask) {
    __shared__ float w1s[32 * 16];
    for (int t = threadIdx.x; t < K * 16 && t < 512; t += 256) w1s[t] = W1[t];
    __syncthreads();
    int row = blockIdx.x * 16 + (threadIdx.x >> 4);
    int c = threadIdx.x & 15;
    if (row >= N) return;
    int beg = offsets[row], end = offsets[row + 1];
    float acc = 0.f;
    for (int base = beg; base < end; base += 16) {
        int cnt = end - base; if (cnt > 16) cnt = 16;
        unsigned ev = entries[base + (c < cnt ? c : cnt - 1)];
        float xv = x[ev & mask];
        for (int j = 0; j < cnt; ++j) {
            unsigned pk = __shfl(ev, j, 16);
            float xj = __shfl(xv, j, 16);
            acc = fmaf(xj, w1s[(int)((pk >> shift) << 4) | c], acc);
        }
    }
    float scale = g1[c] * rsqrtf(v1[c] + EPSBN);
    float bias = b1[c] - m1[c] * scale;
    h[(size_t)row * 16 + c] = __float2half(elu1(acc * scale + bias));
}

// ============================================================================
// Last-resort fallback: atomic path (fp32 throughout)
// ============================================================================

__global__ void s1_scatter_slab(const float* __restrict__ x, const int* __restrict__ in_idx,
                                const int* __restrict__ out_idx, float* __restrict__ s, int M, int N) {
    int m = blockIdx.x * blockDim.x + threadIdx.x;
    if (m >= M) return;
    int k = blockIdx.y;
    size_t e = (size_t)k * M + m;
    unsafeAtomicAdd(&s[(size_t)k * N + out_idx[e]], x[in_idx[e]]);
}

__global__ void s1_combine(const float* __restrict__ s, const float* __restrict__ W1,
                           const float* __restrict__ g1, const float* __restrict__ b1,
                           const float* __restrict__ m1, const float* __restrict__ v1,
                           float* __restrict__ h, int N, int K) {
    __shared__ float w[32 * 16];
    __shared__ float sc[16], bi[16];
    for (int t = threadIdx.x; t < K * 16; t += blockDim.x) w[t] = W1[t];
    if (threadIdx.x < 16) {
        float scale = g1[threadIdx.x] * rsqrtf(v1[threadIdx.x] + EPSBN);
        sc[threadIdx.x] = scale;
        bi[threadIdx.x] = b1[threadIdx.x] - m1[threadIdx.x] * scale;
    }
    __syncthreads();
    int n = blockIdx.x * blockDim.x + threadIdx.x;
    if (n >= N) return;
    float acc[16];
#pragma unroll
    for (int c = 0; c < 16; ++c) acc[c] = 0.f;
    for (int k = 0; k < K; ++k) {
        float sv = s[(size_t)k * N + n];
#pragma unroll
        for (int c = 0; c < 16; ++c) acc[c] = fmaf(sv, w[k * 16 + c], acc[c]);
    }
    float4* hv = (float4*)(h + (size_t)n * 16);
#pragma unroll
    for (int q = 0; q < 4; ++q) {
        float4 o;
        o.x = elu1(acc[q * 4 + 0] * sc[q * 4 + 0] + bi[q * 4 + 0]);
        o.y = elu1(acc[q * 4 + 1] * sc[q * 4 + 1] + bi[q * 4 + 1]);
        o.z = elu1(acc[q * 4 + 2] * sc[q * 4 + 2] + bi[q * 4 + 2]);
        o.w = elu1(acc[q * 4 + 3] * sc[q * 4 + 3] + bi[q * 4 + 3]);
        hv[q] = o;
    }
}

__global__ void bn_elu_c(float* __restrict__ buf, const float* __restrict__ g,
                         const float* __restrict__ b, const float* __restrict__ m,
                         const float* __restrict__ v, size_t total, int cmask) {
    size_t i = (size_t)blockIdx.x * blockDim.x + threadIdx.x;
    if (i >= total) return;
    int c = (int)(i & (size_t)cmask);
    float scale = g[c] * rsqrtf(v[c] + EPSBN);
    buf[i] = elu1((buf[i] - m[c]) * scale + b[c]);
}

__global__ void s2_scatter(const float* __restrict__ h, const float* __restrict__ W2,
                           const int* __restrict__ in_idx, const int* __restrict__ out_idx,
                           float* __restrict__ acc, int M) {
    __shared__ float w[16 * 32];
    int k = blockIdx.y;
    for (int t = threadIdx.x; t < 512; t += blockDim.x) w[t] = W2[(size_t)k * 512 + t];
    __syncthreads();
    int m = blockIdx.x * blockDim.x + threadIdx.x;
    if (m >= M) return;
    size_t e = (size_t)k * M + m;
    int in = in_idx[e], out = out_idx[e];
    const float4* hr = (const float4*)(h + (size_t)in * 16);
    float4 h0 = hr[0], h1 = hr[1], h2 = hr[2], h3 = hr[3];
    float hrow[16] = {h0.x, h0.y, h0.z, h0.w, h1.x, h1.y, h1.z, h1.w,
                      h2.x, h2.y, h2.z, h2.w, h3.x, h3.y, h3.z, h3.w};
    float yv[32];
#pragma unroll
    for (int dd = 0; dd < 32; ++dd) yv[dd] = 0.f;
#pragma unroll
    for (int c = 0; c < 16; ++c) {
        float hv = hrow[c];
#pragma unroll
        for (int dd = 0; dd < 32; ++dd) yv[dd] = fmaf(hv, w[c * 32 + dd], yv[dd]);
    }
    float* ar = acc + (size_t)out * 32;
#pragma unroll
    for (int dd = 0; dd < 32; ++dd) unsafeAtomicAdd(&ar[dd], yv[dd]);
}

// ============================================================================

extern "C" void kernel_launch(void* const* d_in, const int* in_sizes, int n_in,
                              void* d_out, int out_size, void* d_ws, size_t ws_size,
                              hipStream_t stream) {
    const float* x  = (const float*)d_in[0];
    const float* W1 = (const float*)d_in[1];
    const float* g1 = (const float*)d_in[2];
    const float* b1 = (const float*)d_in[3];
    const float* m1 = (const float*)d_in[4];
    const float* v1 = (const float*)d_in[5];
    const float* W2 = (const float*)d_in[6];
    const float* g2 = (const float*)d_in[7];
    const float* b2 = (const float*)d_in[8];
    const float* m2 = (const float*)d_in[9];
    const float* v2 = (const float*)d_in[10];
    const int* in_idx  = (const int*)d_in[11];
    const int* out_idx = (const int*)d_in[12];

    const int N  = in_sizes[0];
    const int C1 = in_sizes[2];           // 16
    const int K  = in_sizes[1] / C1;      // 27
    const int M  = in_sizes[11] / K;      // 200000
    const int E  = K * M;                 // 5.4M
    const int nb = (N + 255) / 256;
    const int NB = (N + 255) >> 8;        // radix buckets (256 rows each)

    float* out = (float*)d_out;
    dim3 blk(256);
    dim3 grdKM((M + 255) / 256, K);

    auto align256 = [](size_t v) { return (v + 255) & ~(size_t)255; };

    // ---- radix layout ----
    size_t bcntB  = align256((size_t)NB * 4);
    size_t bbaseB = align256((size_t)(NB + 1) * 4);
    size_t bcurB  = align256((size_t)NB * 16 * 4);
    size_t tmpB   = align256((size_t)E * 4);
    size_t entB   = align256((size_t)E * 4);
    size_t offB   = align256((size_t)(N + 1) * 4);
    size_t w2tB   = align256((size_t)K * 512 * 2);
    size_t hB     = align256((size_t)N * 16 * 2);
    size_t radixNeed = bcntB + bbaseB + bcurB + tmpB + entB + offB + w2tB + hB;

    bool canRadix = (N <= (1 << 19)) && (K <= 32) && (NB <= NBMAX) && (ws_size >= radixNeed);

    if (canRadix) {
        char* p = (char*)d_ws;
        int* bcnt       = (int*)p;            p += bcntB;
        int* bbase      = (int*)p;            p += bbaseB;
        int* bcur       = (int*)p;            p += bcurB;
        unsigned* tmp   = (unsigned*)p;       p += tmpB;
        unsigned* ent   = (unsigned*)p;       p += entB;
        int* offsets    = (int*)p;            p += offB;
        __half* W2T     = (__half*)p;         p += w2tB;
        __half* h       = (__half*)p;

        hipMemsetAsync(bcnt, 0, (size_t)NB * 4, stream);
        bhist_lds<<<dim3((M + 256 * TPT - 1) / (256 * TPT), K), blk, 0, stream>>>(out_idx, bcnt, M, NB);
        transpose_W2<<<dim3((K * 512 + 255) / 256), blk, 0, stream>>>(W2, W2T, K * 512);
        bscan<<<dim3(1), blk, 0, stream>>>(bcnt, bbase, bcur, NB, E);
        passA<<<dim3((M + 256 * TPT - 1) / (256 * TPT), K), blk, 0, stream>>>(in_idx, out_idx, bcur, tmp, M, NB);
        passB2<<<dim3(NB), blk, 0, stream>>>(tmp, bbase, ent, offsets, x, W1, g1, b1, m1, v1, h, N, K, E, NB);
        s2_gather_v3<<<dim3((N + 31) / 32), dim3(1024), 0, stream>>>(h, W2T, g2, b2, m2, v2, offsets, ent, out, N, K, 19, 0x7FFFFu);
        return;
    }

    // ---- non-radix CSR layout ----
    size_t cntB   = align256((size_t)N * 4);
    size_t bsumB  = align256((size_t)nb * 4);
    size_t curB   = align256((size_t)N * 4);
    size_t csrNeed = cntB + offB + bsumB + entB + w2tB + hB + curB;
    bool canCSR = (N < (1 << 24)) && (K < 256) && (ws_size >= csrNeed);

    if (canCSR) {
        char* p = (char*)d_ws;
        int* cnt        = (int*)p;            p += cntB;
        int* offsets    = (int*)p;            p += offB;
        int* bsum       = (int*)p;            p += bsumB;
        unsigned* ent   = (unsigned*)p;       p += entB;
        __half* W2T     = (__half*)p;         p += w2tB;
        __half* h       = (__half*)p;         p += hB;
        int* cursor     = (int*)p;

        hipMemsetAsync(cnt, 0, (size_t)N * 4, stream);
        hist_kernel<<<dim3((M / 4 + 256) / 256, K), blk, 0, stream>>>(out_idx, cnt, M);
        transpose_W2<<<dim3((K * 512 + 255) / 256), blk, 0, stream>>>(W2, W2T, K * 512);
        scan_block_sums<<<dim3(nb), blk, 0, stream>>>(cnt, bsum, N);
        scan_bsums<<<dim3(1), blk, 0, stream>>>(bsum, nb, offsets, N, E);
        scan_final<<<dim3(nb), blk, 0, stream>>>(cnt, bsum, offsets, cursor, N);
        scatter_entries<<<grdKM, blk, 0, stream>>>(in_idx, out_idx, cursor, ent, M, 24);
        s1_gather_v2<<<dim3((N + 15) / 16), blk, 0, stream>>>(x, W1, g1, b1, m1, v1, offsets, ent, h, N, K, 24, 0xFFFFFFu);
        if (K <= 32)
            s2_gather_v3<<<dim3((N + 31) / 32), dim3(1024), 0, stream>>>(h, W2T, g2, b2, m2, v2, offsets, ent, out, N, K, 24, 0xFFFFFFu);
        else
            s2_gather_v2<<<dim3((N + 7) / 8), blk, 0, stream>>>(h, W2T, g2, b2, m2, v2, offsets, ent, out, N, 24, 0xFFFFFFu);
        return;
    }

    // ---- last-resort atomic path ----
    size_t sBytes = align256((size_t)K * N * 4);
    size_t hBytes = (size_t)N * 16 * 4;
    float* hf = (float*)d_ws;
    if (ws_size >= sBytes + hBytes) {
        float* s = (float*)d_ws;
        hf = (float*)((char*)d_ws + sBytes);
        hipMemsetAsync(s, 0, (size_t)K * N * 4, stream);
        s1_scatter_slab<<<grdKM, blk, 0, stream>>>(x, in_idx, out_idx, s, M, N);
        s1_combine<<<dim3((N + 255) / 256), blk, 0, stream>>>(s, W1, g1, b1, m1, v1, hf, N, K);
    }
    hipMemsetAsync(out, 0, (size_t)N * 32 * 4, stream);
    s2_scatter<<<grdKM, blk, 0, stream>>>(hf, W2, in_idx, out_idx, out, M);
    size_t tot2 = (size_t)N * 32;
    bn_elu_c<<<dim3((unsigned)((tot2 + 255) / 256)), blk, 0, stream>>>(out, g2, b2, m2, v2, tot2, 31);
}

// Round 14
// 401.839 us; speedup vs baseline: 1.0809x; 1.0809x over previous
//
#include <hip/hip_runtime.h>
#include <hip/hip_fp16.h>
#include <math.h>

#define EPSBN 1e-5f
#define NBMAX 2048          // max buckets (256 rows each) for radix path
#define TPT 32              // entries per thread in passA/bhist
#define CAPB 8192           // passB2 LDS staging capacity (entries)

typedef int int4v __attribute__((ext_vector_type(4)));

__device__ __forceinline__ float elu1(float x) { return x > 0.f ? x : expm1f(x); }

// dot of 8 half pairs (packed in float4 bit patterns), fp32 accumulate
__device__ __forceinline__ float dot8h(float4 hv, float4 wv, float acc) {
#if defined(__has_builtin)
#if __has_builtin(__builtin_amdgcn_fdot2)
    typedef _Float16 h2v __attribute__((ext_vector_type(2)));
    union { float4 f; h2v h[4]; } a, b;
    a.f = hv; b.f = wv;
#pragma unroll
    for (int i = 0; i < 4; ++i)
        acc = __builtin_amdgcn_fdot2(a.h[i], b.h[i], acc, false);
    return acc;
#endif
#endif
    const __half2* ha = (const __half2*)&hv;
    const __half2* wa = (const __half2*)&wv;
#pragma unroll
    for (int i = 0; i < 4; ++i) {
        float2 hf = __half22float2(ha[i]);
        float2 wf = __half22float2(wa[i]);
        acc = fmaf(hf.x, wf.x, acc);
        acc = fmaf(hf.y, wf.y, acc);
    }
    return acc;
}

// ============================================================================
// Radix path: bucket histogram (LDS, vectorized reads) + tiny scan (+cursor init)
// ============================================================================

__global__ void bhist_lds(const int* __restrict__ out_idx, int* __restrict__ bcnt, int M, int NB) {
    __shared__ int hcnt[NBMAX];
    for (int t = threadIdx.x; t < NB; t += 256) hcnt[t] = 0;
    __syncthreads();
    int k = blockIdx.y;
    const size_t koff = (size_t)k * M;
    int base = blockIdx.x * (256 * TPT);
    bool vec = (M & 3) == 0;
#pragma unroll
    for (int jj = 0; jj < TPT / 4; ++jj) {
        int m0 = base + (jj * 256 + (int)threadIdx.x) * 4;
        if (vec && m0 + 3 < M) {
            int4v v = *(const int4v*)(out_idx + koff + m0);
            atomicAdd(&hcnt[(unsigned)v.x >> 8], 1);
            atomicAdd(&hcnt[(unsigned)v.y >> 8], 1);
            atomicAdd(&hcnt[(unsigned)v.z >> 8], 1);
            atomicAdd(&hcnt[(unsigned)v.w >> 8], 1);
        } else {
            for (int q = 0; q < 4; ++q) {
                int m = m0 + q;
                if (m < M) atomicAdd(&hcnt[out_idx[koff + m] >> 8], 1);
            }
        }
    }
    __syncthreads();
    for (int t = threadIdx.x; t < NB; t += 256) {
        int c = hcnt[t];
        if (c) atomicAdd(&bcnt[t], c);
    }
}

// single block: exclusive scan of bucket counts -> bbase[0..NB] + padded cursors
__global__ void bscan(const int* __restrict__ bcnt, int* __restrict__ bbase,
                      int* __restrict__ bcur, int NB, int E) {
    __shared__ int tmp[256];
    int carry = 0;
    for (int base = 0; base < NB; base += 256) {
        int i = base + threadIdx.x;
        int v = (i < NB) ? bcnt[i] : 0;
        tmp[threadIdx.x] = v;
        __syncthreads();
        for (int off = 1; off < 256; off <<= 1) {
            int t = (threadIdx.x >= off) ? tmp[threadIdx.x - off] : 0;
            __syncthreads();
            tmp[threadIdx.x] += t;
            __syncthreads();
        }
        if (i < NB) {
            int ex = tmp[threadIdx.x] - v + carry;
            bbase[i] = ex;
            bcur[i * 16] = ex;
        }
        carry += tmp[255];
        __syncthreads();
    }
    if (threadIdx.x == 0) bbase[NB] = E;
}

// ============================================================================
// passA: bucket scatter (vectorized reads). tmp[pos] = (out&255)<<24|k<<19|in
// ============================================================================

__global__ void passA(const int* __restrict__ in_idx, const int* __restrict__ out_idx,
                      int* __restrict__ bcur, unsigned* __restrict__ tmp, int M, int NB) {
    __shared__ int cnt[NBMAX];
    __shared__ int gbase[NBMAX];
    for (int t = threadIdx.x; t < NB; t += 256) cnt[t] = 0;
    __syncthreads();
    int k = blockIdx.y;
    const size_t koff = (size_t)k * M;
    int base = blockIdx.x * (256 * TPT);
    unsigned pk[TPT];
    int bk[TPT];
    bool vec = (M & 3) == 0;
#pragma unroll
    for (int jj = 0; jj < TPT / 4; ++jj) {
        int m0 = base + (jj * 256 + (int)threadIdx.x) * 4;
        if (vec && m0 + 3 < M) {
            int4v vi = *(const int4v*)(in_idx + koff + m0);
            int4v vo = *(const int4v*)(out_idx + koff + m0);
#pragma unroll
            for (int q = 0; q < 4; ++q) {
                unsigned in = (unsigned)vi[q];
                unsigned out = (unsigned)vo[q];
                pk[jj * 4 + q] = ((out & 255u) << 24) | ((unsigned)k << 19) | in;
                bk[jj * 4 + q] = (int)(out >> 8);
                atomicAdd(&cnt[bk[jj * 4 + q]], 1);
            }
        } else {
#pragma unroll
            for (int q = 0; q < 4; ++q) {
                int m = m0 + q;
                if (m < M) {
                    unsigned in = (unsigned)in_idx[koff + m];
                    unsigned out = (unsigned)out_idx[koff + m];
                    pk[jj * 4 + q] = ((out & 255u) << 24) | ((unsigned)k << 19) | in;
                    bk[jj * 4 + q] = (int)(out >> 8);
                    atomicAdd(&cnt[bk[jj * 4 + q]], 1);
                } else bk[jj * 4 + q] = -1;
            }
        }
    }
    __syncthreads();
    for (int b = threadIdx.x; b < NB; b += 256) {
        int c = cnt[b];
        gbase[b] = c ? atomicAdd(&bcur[b * 16], c) : 0;
        cnt[b] = 0;   // reuse as local slot cursor
    }
    __syncthreads();
#pragma unroll
    for (int j = 0; j < TPT; ++j) {
        if (bk[j] >= 0) {
            int slot = atomicAdd(&cnt[bk[j]], 1);
            tmp[gbase[bk[j]] + slot] = pk[j];
        }
    }
}

// ============================================================================
// passB2: per bucket — row counting-sort (LDS), write entries + offsets,
// and FUSED stage-1: one thread per row computes h from LDS-resident entries.
// ============================================================================

__global__ void passB2(const unsigned* __restrict__ tmp, const int* __restrict__ bbase,
                       unsigned* __restrict__ entries, int* __restrict__ offsets,
                       const float* __restrict__ x, const float* __restrict__ W1,
                       const float* __restrict__ g1, const float* __restrict__ b1,
                       const float* __restrict__ m1, const float* __restrict__ v1,
                       __half* __restrict__ h, int N, int K, int E, int NB) {
    __shared__ unsigned stg[CAPB];
    __shared__ int rcnt[256], rbase[256], rcur[256], sc[256];
    __shared__ float w1s[32 * 16];
    __shared__ float scb[16], bib[16];
    int b = blockIdx.x;
    int r0 = b << 8;
    int nr = N - r0; if (nr > 256) nr = 256;
    int gbeg = bbase[b], gend = bbase[b + 1];
    int count = gend - gbeg;
    for (int t = threadIdx.x; t < K * 16; t += 256) w1s[t] = W1[t];
    if (threadIdx.x < 16) {
        float scale = g1[threadIdx.x] * rsqrtf(v1[threadIdx.x] + EPSBN);
        scb[threadIdx.x] = scale;
        bib[threadIdx.x] = b1[threadIdx.x] - m1[threadIdx.x] * scale;
    }
    rcnt[threadIdx.x] = 0;
    __syncthreads();
    for (int i = threadIdx.x; i < count; i += 256)
        atomicAdd(&rcnt[tmp[gbeg + i] >> 24], 1);
    __syncthreads();
    int v = rcnt[threadIdx.x];
    sc[threadIdx.x] = v;
    __syncthreads();
    for (int off = 1; off < 256; off <<= 1) {
        int t = (threadIdx.x >= off) ? sc[threadIdx.x - off] : 0;
        __syncthreads();
        sc[threadIdx.x] += t;
        __syncthreads();
    }
    rbase[threadIdx.x] = sc[threadIdx.x] - v;
    rcur[threadIdx.x] = sc[threadIdx.x] - v;
    if (threadIdx.x < nr) offsets[r0 + threadIdx.x] = gbeg + rbase[threadIdx.x];
    if (b == NB - 1 && threadIdx.x == 0) offsets[N] = E;
    __syncthreads();

    if (count <= CAPB) {
        for (int i = threadIdx.x; i < count; i += 256) {
            unsigned vv = tmp[gbeg + i];
            int slot = atomicAdd(&rcur[vv >> 24], 1);
            stg[slot] = vv & 0x00FFFFFFu;
        }
        __syncthreads();
        for (int i = threadIdx.x; i < count; i += 256)
            entries[gbeg + i] = stg[i];
        if (threadIdx.x < nr) {
            float acc[16];
#pragma unroll
            for (int c = 0; c < 16; ++c) acc[c] = 0.f;
            int rb = rbase[threadIdx.x], re = rb + rcnt[threadIdx.x];
            for (int i = rb; i < re; ++i) {
                unsigned vv = stg[i];
                float xv = x[vv & 0x7FFFFu];
                const float* wr = &w1s[((vv >> 19) & 31) << 4];
#pragma unroll
                for (int c = 0; c < 16; ++c) acc[c] = fmaf(xv, wr[c], acc[c]);
            }
            int row = r0 + threadIdx.x;
            float4 pack[2];
            __half2* hp = (__half2*)pack;
#pragma unroll
            for (int q = 0; q < 8; ++q) {
                __half2 hh;
                hh.x = __float2half(elu1(acc[2 * q] * scb[2 * q] + bib[2 * q]));
                hh.y = __float2half(elu1(acc[2 * q + 1] * scb[2 * q + 1] + bib[2 * q + 1]));
                hp[q] = hh;
            }
            float4* dst = (float4*)(h + (size_t)row * 16);
            dst[0] = pack[0];
            dst[1] = pack[1];
        }
    } else {
        for (int i = threadIdx.x; i < count; i += 256) {
            unsigned vv = tmp[gbeg + i];
            int slot = atomicAdd(&rcur[vv >> 24], 1);
            entries[gbeg + slot] = vv & 0x00FFFFFFu;
        }
        __syncthreads();
        if (threadIdx.x < nr) {
            float acc[16];
#pragma unroll
            for (int c = 0; c < 16; ++c) acc[c] = 0.f;
            int rb = rbase[threadIdx.x], re = rb + rcnt[threadIdx.x];
            for (int i = rb; i < re; ++i) {
                unsigned vv = entries[gbeg + i];
                float xv = x[vv & 0x7FFFFu];
                const float* wr = &w1s[((vv >> 19) & 31) << 4];
#pragma unroll
                for (int c = 0; c < 16; ++c) acc[c] = fmaf(xv, wr[c], acc[c]);
            }
            int row = r0 + threadIdx.x;
            float4 pack[2];
            __half2* hp = (__half2*)pack;
#pragma unroll
            for (int q = 0; q < 8; ++q) {
                __half2 hh;
                hh.x = __float2half(elu1(acc[2 * q] * scb[2 * q] + bib[2 * q]));
                hh.y = __float2half(elu1(acc[2 * q + 1] * scb[2 * q + 1] + bib[2 * q + 1]));
                hp[q] = hh;
            }
            float4* dst = (float4*)(h + (size_t)row * 16);
            dst[0] = pack[0];
            dst[1] = pack[1];
        }
    }
}

// W2T[k][d][c] = (half)W2[k][c][d]  (27 KB, L1-resident)
__global__ void transpose_W2(const float* __restrict__ W2, __half* __restrict__ W2T, int total) {
    int i = blockIdx.x * 256 + threadIdx.x;
    if (i >= total) return;
    int k = i >> 9;
    int r = i & 511;
    int c = r >> 5, d = r & 31;
    W2T[(k << 9) | (d << 4) | c] = __float2half(W2[i]);
}

// ============================================================================
// Stage 2 gather v2 (known-best): one half-wave per row; cooperative
// lane-per-entry h staging into LDS; register-accumulated dots; W2T from L1.
// ============================================================================

__global__ void s2_gather_v2(const __half* __restrict__ h, const __half* __restrict__ W2T,
                             const float* __restrict__ g2, const float* __restrict__ b2,
                             const float* __restrict__ m2, const float* __restrict__ v2,
                             const int* __restrict__ offsets, const unsigned* __restrict__ entries,
                             float* __restrict__ out, int N, int shift, unsigned mask) {
    __shared__ __half stg[8][32 * 16 + 8];   // 1KB staging per half-wave (+pad)
    int hw = threadIdx.x >> 5;
    int lane = threadIdx.x & 31;
    int row = blockIdx.x * 8 + hw;
    if (row >= N) return;
    int d = lane;
    int beg = offsets[row], end = offsets[row + 1];
    float acc = 0.f;
    __half* my = stg[hw];
    for (int base = beg; base < end; base += 32) {
        int cnt = end - base; if (cnt > 32) cnt = 32;
        unsigned ev = entries[base + (lane < cnt ? lane : cnt - 1)];
        if (lane < cnt) {
            const float4* hp = (const float4*)(h + ((size_t)(ev & mask) << 4));
            float4 h0 = hp[0], h1 = hp[1];
            float4* dst = (float4*)(my + lane * 16);
            dst[0] = h0;
            dst[1] = h1;
        }
        asm volatile("s_waitcnt lgkmcnt(0)" ::: "memory");
        int j = 0;
        for (; j + 1 < cnt; j += 2) {
            unsigned pk0 = __shfl(ev, j, 32);
            unsigned pk1 = __shfl(ev, j + 1, 32);
            const float4* hr0 = (const float4*)(my + j * 16);
            const float4* hr1 = (const float4*)(my + (j + 1) * 16);
            float4 ha0 = hr0[0], hb0 = hr0[1];
            float4 ha1 = hr1[0], hb1 = hr1[1];
            const float4* wp0 = (const float4*)(W2T + (((size_t)(pk0 >> shift) << 9) | ((unsigned)d << 4)));
            const float4* wp1 = (const float4*)(W2T + (((size_t)(pk1 >> shift) << 9) | ((unsigned)d << 4)));
            acc = dot8h(ha0, wp0[0], acc);
            acc = dot8h(hb0, wp0[1], acc);
            acc = dot8h(ha1, wp1[0], acc);
            acc = dot8h(hb1, wp1[1], acc);
        }
        if (j < cnt) {
            unsigned pk0 = __shfl(ev, j, 32);
            const float4* hr0 = (const float4*)(my + j * 16);
            float4 ha0 = hr0[0], hb0 = hr0[1];
            const float4* wp0 = (const float4*)(W2T + (((size_t)(pk0 >> shift) << 9) | ((unsigned)d << 4)));
            acc = dot8h(ha0, wp0[0], acc);
            acc = dot8h(hb0, wp0[1], acc);
        }
        asm volatile("s_waitcnt lgkmcnt(0)" ::: "memory");
    }
    float scale = g2[d] * rsqrtf(v2[d] + EPSBN);
    float bias = b2[d] - m2[d] * scale;
    out[(size_t)row * 32 + d] = elu1(acc * scale + bias);
}

// ============================================================================
// Non-radix CSR fallback kernels
// ============================================================================

__global__ void hist_kernel(const int* __restrict__ out_idx, int* __restrict__ cnt, int M) {
    int m = (blockIdx.x * blockDim.x + threadIdx.x) * 4;
    if (m >= M) return;
    size_t e = (size_t)blockIdx.y * M + m;
    if (m + 3 < M && ((M & 3) == 0)) {
        int4v v = *(const int4v*)(out_idx + e);
        atomicAdd(&cnt[v.x], 1);
        atomicAdd(&cnt[v.y], 1);
        atomicAdd(&cnt[v.z], 1);
        atomicAdd(&cnt[v.w], 1);
    } else {
        for (int j = 0; j < M - m && j < 4; ++j) atomicAdd(&cnt[out_idx[e + j]], 1);
    }
}

__global__ void scan_block_sums(const int* __restrict__ cnt, int* __restrict__ bsum, int N) {
    __shared__ int tmp[256];
    int i = blockIdx.x * 256 + threadIdx.x;
    tmp[threadIdx.x] = (i < N) ? cnt[i] : 0;
    __syncthreads();
    for (int off = 128; off > 0; off >>= 1) {
        if (threadIdx.x < off) tmp[threadIdx.x] += tmp[threadIdx.x + off];
        __syncthreads();
    }
    if (threadIdx.x == 0) bsum[blockIdx.x] = tmp[0];
}

__global__ void scan_bsums(int* __restrict__ bsum, int nb, int* __restrict__ offsets, int N, int E) {
    __shared__ int tmp[256];
    int carry = 0;
    for (int base = 0; base < nb; base += 256) {
        int i = base + threadIdx.x;
        int v = (i < nb) ? bsum[i] : 0;
        tmp[threadIdx.x] = v;
        __syncthreads();
        for (int off = 1; off < 256; off <<= 1) {
            int t = (threadIdx.x >= off) ? tmp[threadIdx.x - off] : 0;
            __syncthreads();
            tmp[threadIdx.x] += t;
            __syncthreads();
        }
        int incl = tmp[threadIdx.x];
        int total = tmp[255];
        if (i < nb) bsum[i] = incl - v + carry;
        carry += total;
        __syncthreads();
    }
    if (threadIdx.x == 0) offsets[N] = E;
}

__global__ void scan_final(const int* __restrict__ cnt, const int* __restrict__ bsum,
                           int* __restrict__ offsets, int* __restrict__ cursor, int N) {
    __shared__ int tmp[256];
    int i = blockIdx.x * 256 + threadIdx.x;
    int v = (i < N) ? cnt[i] : 0;
    tmp[threadIdx.x] = v;
    __syncthreads();
    for (int off = 1; off < 256; off <<= 1) {
        int t = (threadIdx.x >= off) ? tmp[threadIdx.x - off] : 0;
        __syncthreads();
        tmp[threadIdx.x] += t;
        __syncthreads();
    }
    if (i < N) {
        int o = tmp[threadIdx.x] - v + bsum[blockIdx.x];
        offsets[i] = o;
        cursor[i] = o;
    }
}

__global__ void scatter_entries(const int* __restrict__ in_idx, const int* __restrict__ out_idx,
                                int* __restrict__ cursor, unsigned* __restrict__ entries, int M, int shift) {
    int m = blockIdx.x * blockDim.x + threadIdx.x;
    if (m >= M) return;
    int k = blockIdx.y;
    size_t e = (size_t)k * M + m;
    int pos = atomicAdd(&cursor[out_idx[e]], 1);
    entries[pos] = (unsigned)in_idx[e] | ((unsigned)k << shift);
}

__global__ void s1_gather_v2(const float* __restrict__ x, const float* __restrict__ W1,
                             const float* __restrict__ g1, const float* __restrict__ b1,
                             const float* __restrict__ m1, const float* __restrict__ v1,
                             const int* __restrict__ offsets, const unsigned* __restrict__ entries,
                             __half* __restrict__ h, int N, int K, int shift, unsigned mask) {
    __shared__ float w1s[32 * 16];
    for (int t = threadIdx.x; t < K * 16 && t < 512; t += 256) w1s[t] = W1[t];
    __syncthreads();
    int row = blockIdx.x * 16 + (threadIdx.x >> 4);
    int c = threadIdx.x & 15;
    if (row >= N) return;
    int beg = offsets[row], end = offsets[row + 1];
    float acc = 0.f;
    for (int base = beg; base < end; base += 16) {
        int cnt = end - base; if (cnt > 16) cnt = 16;
        unsigned ev = entries[base + (c < cnt ? c : cnt - 1)];
        float xv = x[ev & mask];
        for (int j = 0; j < cnt; ++j) {
            unsigned pk = __shfl(ev, j, 16);
            float xj = __shfl(xv, j, 16);
            acc = fmaf(xj, w1s[(int)((pk >> shift) << 4) | c], acc);
        }
    }
    float scale = g1[c] * rsqrtf(v1[c] + EPSBN);
    float bias = b1[c] - m1[c] * scale;
    h[(size_t)row * 16 + c] = __float2half(elu1(acc * scale + bias));
}

// ============================================================================
// Last-resort fallback: atomic path (fp32 throughout)
// ============================================================================

__global__ void s1_scatter_slab(const float* __restrict__ x, const int* __restrict__ in_idx,
                                const int* __restrict__ out_idx, float* __restrict__ s, int M, int N) {
    int m = blockIdx.x * blockDim.x + threadIdx.x;
    if (m >= M) return;
    int k = blockIdx.y;
    size_t e = (size_t)k * M + m;
    unsafeAtomicAdd(&s[(size_t)k * N + out_idx[e]], x[in_idx[e]]);
}

__global__ void s1_combine(const float* __restrict__ s, const float* __restrict__ W1,
                           const float* __restrict__ g1, const float* __restrict__ b1,
                           const float* __restrict__ m1, const float* __restrict__ v1,
                           float* __restrict__ h, int N, int K) {
    __shared__ float w[32 * 16];
    __shared__ float sc[16], bi[16];
    for (int t = threadIdx.x; t < K * 16; t += blockDim.x) w[t] = W1[t];
    if (threadIdx.x < 16) {
        float scale = g1[threadIdx.x] * rsqrtf(v1[threadIdx.x] + EPSBN);
        sc[threadIdx.x] = scale;
        bi[threadIdx.x] = b1[threadIdx.x] - m1[threadIdx.x] * scale;
    }
    __syncthreads();
    int n = blockIdx.x * blockDim.x + threadIdx.x;
    if (n >= N) return;
    float acc[16];
#pragma unroll
    for (int c = 0; c < 16; ++c) acc[c] = 0.f;
    for (int k = 0; k < K; ++k) {
        float sv = s[(size_t)k * N + n];
#pragma unroll
        for (int c = 0; c < 16; ++c) acc[c] = fmaf(sv, w[k * 16 + c], acc[c]);
    }
    float4* hv = (float4*)(h + (size_t)n * 16);
#pragma unroll
    for (int q = 0; q < 4; ++q) {
        float4 o;
        o.x = elu1(acc[q * 4 + 0] * sc[q * 4 + 0] + bi[q * 4 + 0]);
        o.y = elu1(acc[q * 4 + 1] * sc[q * 4 + 1] + bi[q * 4 + 1]);
        o.z = elu1(acc[q * 4 + 2] * sc[q * 4 + 2] + bi[q * 4 + 2]);
        o.w = elu1(acc[q * 4 + 3] * sc[q * 4 + 3] + bi[q * 4 + 3]);
        hv[q] = o;
    }
}

__global__ void bn_elu_c(float* __restrict__ buf, const float* __restrict__ g,
                         const float* __restrict__ b, const float* __restrict__ m,
                         const float* __restrict__ v, size_t total, int cmask) {
    size_t i = (size_t)blockIdx.x * blockDim.x + threadIdx.x;
    if (i >= total) return;
    int c = (int)(i & (size_t)cmask);
    float scale = g[c] * rsqrtf(v[c] + EPSBN);
    buf[i] = elu1((buf[i] - m[c]) * scale + b[c]);
}

__global__ void s2_scatter(const float* __restrict__ h, const float* __restrict__ W2,
                           const int* __restrict__ in_idx, const int* __restrict__ out_idx,
                           float* __restrict__ acc, int M) {
    __shared__ float w[16 * 32];
    int k = blockIdx.y;
    for (int t = threadIdx.x; t < 512; t += blockDim.x) w[t] = W2[(size_t)k * 512 + t];
    __syncthreads();
    int m = blockIdx.x * blockDim.x + threadIdx.x;
    if (m >= M) return;
    size_t e = (size_t)k * M + m;
    int in = in_idx[e], out = out_idx[e];
    const float4* hr = (const float4*)(h + (size_t)in * 16);
    float4 h0 = hr[0], h1 = hr[1], h2 = hr[2], h3 = hr[3];
    float hrow[16] = {h0.x, h0.y, h0.z, h0.w, h1.x, h1.y, h1.z, h1.w,
                      h2.x, h2.y, h2.z, h2.w, h3.x, h3.y, h3.z, h3.w};
    float yv[32];
#pragma unroll
    for (int dd = 0; dd < 32; ++dd) yv[dd] = 0.f;
#pragma unroll
    for (int c = 0; c < 16; ++c) {
        float hv = hrow[c];
#pragma unroll
        for (int dd = 0; dd < 32; ++dd) yv[dd] = fmaf(hv, w[c * 32 + dd], yv[dd]);
    }
    float* ar = acc + (size_t)out * 32;
#pragma unroll
    for (int dd = 0; dd < 32; ++dd) unsafeAtomicAdd(&ar[dd], yv[dd]);
}

// ============================================================================

extern "C" void kernel_launch(void* const* d_in, const int* in_sizes, int n_in,
                              void* d_out, int out_size, void* d_ws, size_t ws_size,
                              hipStream_t stream) {
    const float* x  = (const float*)d_in[0];
    const float* W1 = (const float*)d_in[1];
    const float* g1 = (const float*)d_in[2];
    const float* b1 = (const float*)d_in[3];
    const float* m1 = (const float*)d_in[4];
    const float* v1 = (const float*)d_in[5];
    const float* W2 = (const float*)d_in[6];
    const float* g2 = (const float*)d_in[7];
    const float* b2 = (const float*)d_in[8];
    const float* m2 = (const float*)d_in[9];
    const float* v2 = (const float*)d_in[10];
    const int* in_idx  = (const int*)d_in[11];
    const int* out_idx = (const int*)d_in[12];

    const int N  = in_sizes[0];
    const int C1 = in_sizes[2];           // 16
    const int K  = in_sizes[1] / C1;      // 27
    const int M  = in_sizes[11] / K;      // 200000
    const int E  = K * M;                 // 5.4M
    const int nb = (N + 255) / 256;
    const int NB = (N + 255) >> 8;        // radix buckets (256 rows each)

    float* out = (float*)d_out;
    dim3 blk(256);
    dim3 grdKM((M + 255) / 256, K);

    auto align256 = [](size_t v) { return (v + 255) & ~(size_t)255; };

    // ---- radix layout ----
    size_t bcntB  = align256((size_t)NB * 4);
    size_t bbaseB = align256((size_t)(NB + 1) * 4);
    size_t bcurB  = align256((size_t)NB * 16 * 4);
    size_t tmpB   = align256((size_t)E * 4);
    size_t entB   = align256((size_t)E * 4);
    size_t offB   = align256((size_t)(N + 1) * 4);
    size_t w2tB   = align256((size_t)K * 512 * 2);
    size_t hB     = align256((size_t)N * 16 * 2);
    size_t radixNeed = bcntB + bbaseB + bcurB + tmpB + entB + offB + w2tB + hB;

    bool canRadix = (N <= (1 << 19)) && (K <= 32) && (NB <= NBMAX) && (ws_size >= radixNeed);

    if (canRadix) {
        char* p = (char*)d_ws;
        int* bcnt       = (int*)p;            p += bcntB;
        int* bbase      = (int*)p;            p += bbaseB;
        int* bcur       = (int*)p;            p += bcurB;
        unsigned* tmp   = (unsigned*)p;       p += tmpB;
        unsigned* ent   = (unsigned*)p;       p += entB;
        int* offsets    = (int*)p;            p += offB;
        __half* W2T     = (__half*)p;         p += w2tB;
        __half* h       = (__half*)p;

        hipMemsetAsync(bcnt, 0, (size_t)NB * 4, stream);
        bhist_lds<<<dim3((M + 256 * TPT - 1) / (256 * TPT), K), blk, 0, stream>>>(out_idx, bcnt, M, NB);
        transpose_W2<<<dim3((K * 512 + 255) / 256), blk, 0, stream>>>(W2, W2T, K * 512);
        bscan<<<dim3(1), blk, 0, stream>>>(bcnt, bbase, bcur, NB, E);
        passA<<<dim3((M + 256 * TPT - 1) / (256 * TPT), K), blk, 0, stream>>>(in_idx, out_idx, bcur, tmp, M, NB);
        passB2<<<dim3(NB), blk, 0, stream>>>(tmp, bbase, ent, offsets, x, W1, g1, b1, m1, v1, h, N, K, E, NB);
        s2_gather_v2<<<dim3((N + 7) / 8), blk, 0, stream>>>(h, W2T, g2, b2, m2, v2, offsets, ent, out, N, 19, 0x7FFFFu);
        return;
    }

    // ---- non-radix CSR layout ----
    size_t cntB   = align256((size_t)N * 4);
    size_t bsumB  = align256((size_t)nb * 4);
    size_t curB   = align256((size_t)N * 4);
    size_t csrNeed = cntB + offB + bsumB + entB + w2tB + hB + curB;
    bool canCSR = (N < (1 << 24)) && (K < 256) && (ws_size >= csrNeed);

    if (canCSR) {
        char* p = (char*)d_ws;
        int* cnt        = (int*)p;            p += cntB;
        int* offsets    = (int*)p;            p += offB;
        int* bsum       = (int*)p;            p += bsumB;
        unsigned* ent   = (unsigned*)p;       p += entB;
        __half* W2T     = (__half*)p;         p += w2tB;
        __half* h       = (__half*)p;         p += hB;
        int* cursor     = (int*)p;

        hipMemsetAsync(cnt, 0, (size_t)N * 4, stream);
        hist_kernel<<<dim3((M / 4 + 256) / 256, K), blk, 0, stream>>>(out_idx, cnt, M);
        transpose_W2<<<dim3((K * 512 + 255) / 256), blk, 0, stream>>>(W2, W2T, K * 512);
        scan_block_sums<<<dim3(nb), blk, 0, stream>>>(cnt, bsum, N);
        scan_bsums<<<dim3(1), blk, 0, stream>>>(bsum, nb, offsets, N, E);
        scan_final<<<dim3(nb), blk, 0, stream>>>(cnt, bsum, offsets, cursor, N);
        scatter_entries<<<grdKM, blk, 0, stream>>>(in_idx, out_idx, cursor, ent, M, 24);
        s1_gather_v2<<<dim3((N + 15) / 16), blk, 0, stream>>>(x, W1, g1, b1, m1, v1, offsets, ent, h, N, K, 24, 0xFFFFFFu);
        s2_gather_v2<<<dim3((N + 7) / 8), blk, 0, stream>>>(h, W2T, g2, b2, m2, v2, offsets, ent, out, N, 24, 0xFFFFFFu);
        return;
    }

    // ---- last-resort atomic path ----
    size_t sBytes = align256((size_t)K * N * 4);
    size_t hBytes = (size_t)N * 16 * 4;
    float* hf = (float*)d_ws;
    if (ws_size >= sBytes + hBytes) {
        float* s = (float*)d_ws;
        hf = (float*)((char*)d_ws + sBytes);
        hipMemsetAsync(s, 0, (size_t)K * N * 4, stream);
        s1_scatter_slab<<<grdKM, blk, 0, stream>>>(x, in_idx, out_idx, s, M, N);
        s1_combine<<<dim3((N + 255) / 256), blk, 0, stream>>>(s, W1, g1, b1, m1, v1, hf, N, K);
    }
    hipMemsetAsync(out, 0, (size_t)N * 32 * 4, stream);
    s2_scatter<<<grdKM, blk, 0, stream>>>(hf, W2, in_idx, out_idx, out, M);
    size_t tot2 = (size_t)N * 32;
    bn_elu_c<<<dim3((unsigned)((tot2 + 255) / 256)), blk, 0, stream>>>(out, g2, b2, m2, v2, tot2, 31);
}

// Round 15
// 383.784 us; speedup vs baseline: 1.1317x; 1.0470x over previous
//
#include <hip/hip_runtime.h>
#include <hip/hip_fp16.h>
#include <math.h>

#define EPSBN 1e-5f
#define NBMAX 2048          // max buckets (256 rows each) for radix path
#define TPT 32              // entries per thread in passA/bhist
#define CAPB 8192           // passB2 LDS staging capacity (entries)

typedef int int4v __attribute__((ext_vector_type(4)));

__device__ __forceinline__ float elu1(float x) { return x > 0.f ? x : expm1f(x); }

// dot of 8 half pairs (packed in float4 bit patterns), fp32 accumulate
__device__ __forceinline__ float dot8h(float4 hv, float4 wv, float acc) {
#if defined(__has_builtin)
#if __has_builtin(__builtin_amdgcn_fdot2)
    typedef _Float16 h2v __attribute__((ext_vector_type(2)));
    union { float4 f; h2v h[4]; } a, b;
    a.f = hv; b.f = wv;
#pragma unroll
    for (int i = 0; i < 4; ++i)
        acc = __builtin_amdgcn_fdot2(a.h[i], b.h[i], acc, false);
    return acc;
#endif
#endif
    const __half2* ha = (const __half2*)&hv;
    const __half2* wa = (const __half2*)&wv;
#pragma unroll
    for (int i = 0; i < 4; ++i) {
        float2 hf = __half22float2(ha[i]);
        float2 wf = __half22float2(wa[i]);
        acc = fmaf(hf.x, wf.x, acc);
        acc = fmaf(hf.y, wf.y, acc);
    }
    return acc;
}

// ============================================================================
// Slab-radix path: no pre-histogram. bcur[b*16] = b*CAP; passA scatters into
// per-bucket slabs; bscan2 derives counts from final cursors -> compact prefix.
// ============================================================================

__global__ void init_slab(int* __restrict__ bcur, int NB, int CAP) {
    int b = blockIdx.x * 256 + threadIdx.x;
    if (b >= NB) return;
    bcur[b * 16] = b * CAP;
}

// single block: counts from bcur (minus slab base) -> exclusive prefix bbase
__global__ void bscan2(const int* __restrict__ bcur, int* __restrict__ bbase,
                       int NB, int E, int CAP) {
    __shared__ int tmp[256];
    int carry = 0;
    for (int base = 0; base < NB; base += 256) {
        int i = base + threadIdx.x;
        int v = (i < NB) ? (bcur[i * 16] - i * CAP) : 0;
        tmp[threadIdx.x] = v;
        __syncthreads();
        for (int off = 1; off < 256; off <<= 1) {
            int t = (threadIdx.x >= off) ? tmp[threadIdx.x - off] : 0;
            __syncthreads();
            tmp[threadIdx.x] += t;
            __syncthreads();
        }
        if (i < NB) bbase[i] = tmp[threadIdx.x] - v + carry;
        carry += tmp[255];
        __syncthreads();
    }
    if (threadIdx.x == 0) bbase[NB] = E;
}

// ============================================================================
// bhist-radix fallback pieces (proven round-14 path)
// ============================================================================

__global__ void bhist_lds(const int* __restrict__ out_idx, int* __restrict__ bcnt, int M, int NB) {
    __shared__ int hcnt[NBMAX];
    for (int t = threadIdx.x; t < NB; t += 256) hcnt[t] = 0;
    __syncthreads();
    int k = blockIdx.y;
    const size_t koff = (size_t)k * M;
    int base = blockIdx.x * (256 * TPT);
    bool vec = (M & 3) == 0;
#pragma unroll
    for (int jj = 0; jj < TPT / 4; ++jj) {
        int m0 = base + (jj * 256 + (int)threadIdx.x) * 4;
        if (vec && m0 + 3 < M) {
            int4v v = *(const int4v*)(out_idx + koff + m0);
            atomicAdd(&hcnt[(unsigned)v.x >> 8], 1);
            atomicAdd(&hcnt[(unsigned)v.y >> 8], 1);
            atomicAdd(&hcnt[(unsigned)v.z >> 8], 1);
            atomicAdd(&hcnt[(unsigned)v.w >> 8], 1);
        } else {
            for (int q = 0; q < 4; ++q) {
                int m = m0 + q;
                if (m < M) atomicAdd(&hcnt[out_idx[koff + m] >> 8], 1);
            }
        }
    }
    __syncthreads();
    for (int t = threadIdx.x; t < NB; t += 256) {
        int c = hcnt[t];
        if (c) atomicAdd(&bcnt[t], c);
    }
}

__global__ void bscan(const int* __restrict__ bcnt, int* __restrict__ bbase,
                      int* __restrict__ bcur, int NB, int E) {
    __shared__ int tmp[256];
    int carry = 0;
    for (int base = 0; base < NB; base += 256) {
        int i = base + threadIdx.x;
        int v = (i < NB) ? bcnt[i] : 0;
        tmp[threadIdx.x] = v;
        __syncthreads();
        for (int off = 1; off < 256; off <<= 1) {
            int t = (threadIdx.x >= off) ? tmp[threadIdx.x - off] : 0;
            __syncthreads();
            tmp[threadIdx.x] += t;
            __syncthreads();
        }
        if (i < NB) {
            int ex = tmp[threadIdx.x] - v + carry;
            bbase[i] = ex;
            bcur[i * 16] = ex;
        }
        carry += tmp[255];
        __syncthreads();
    }
    if (threadIdx.x == 0) bbase[NB] = E;
}

// ============================================================================
// passA: bucket scatter (vectorized reads). tmp[pos] = (out&255)<<24|k<<19|in
// ============================================================================

__global__ void passA(const int* __restrict__ in_idx, const int* __restrict__ out_idx,
                      int* __restrict__ bcur, unsigned* __restrict__ tmp, int M, int NB) {
    __shared__ int cnt[NBMAX];
    __shared__ int gbase[NBMAX];
    for (int t = threadIdx.x; t < NB; t += 256) cnt[t] = 0;
    __syncthreads();
    int k = blockIdx.y;
    const size_t koff = (size_t)k * M;
    int base = blockIdx.x * (256 * TPT);
    unsigned pk[TPT];
    int bk[TPT];
    bool vec = (M & 3) == 0;
#pragma unroll
    for (int jj = 0; jj < TPT / 4; ++jj) {
        int m0 = base + (jj * 256 + (int)threadIdx.x) * 4;
        if (vec && m0 + 3 < M) {
            int4v vi = *(const int4v*)(in_idx + koff + m0);
            int4v vo = *(const int4v*)(out_idx + koff + m0);
#pragma unroll
            for (int q = 0; q < 4; ++q) {
                unsigned in = (unsigned)vi[q];
                unsigned out = (unsigned)vo[q];
                pk[jj * 4 + q] = ((out & 255u) << 24) | ((unsigned)k << 19) | in;
                bk[jj * 4 + q] = (int)(out >> 8);
                atomicAdd(&cnt[bk[jj * 4 + q]], 1);
            }
        } else {
#pragma unroll
            for (int q = 0; q < 4; ++q) {
                int m = m0 + q;
                if (m < M) {
                    unsigned in = (unsigned)in_idx[koff + m];
                    unsigned out = (unsigned)out_idx[koff + m];
                    pk[jj * 4 + q] = ((out & 255u) << 24) | ((unsigned)k << 19) | in;
                    bk[jj * 4 + q] = (int)(out >> 8);
                    atomicAdd(&cnt[bk[jj * 4 + q]], 1);
                } else bk[jj * 4 + q] = -1;
            }
        }
    }
    __syncthreads();
    for (int b = threadIdx.x; b < NB; b += 256) {
        int c = cnt[b];
        gbase[b] = c ? atomicAdd(&bcur[b * 16], c) : 0;
        cnt[b] = 0;   // reuse as local slot cursor
    }
    __syncthreads();
#pragma unroll
    for (int j = 0; j < TPT; ++j) {
        if (bk[j] >= 0) {
            int slot = atomicAdd(&cnt[bk[j]], 1);
            tmp[gbase[bk[j]] + slot] = pk[j];
        }
    }
}

// ============================================================================
// passB2: per bucket — row counting-sort (LDS), write entries + offsets,
// FUSED stage-1. CAP>0: tmp is slabbed at b*CAP; CAP==0: tmp compact at bbase.
// ============================================================================

__global__ void passB2(const unsigned* __restrict__ tmp, const int* __restrict__ bbase,
                       unsigned* __restrict__ entries, int* __restrict__ offsets,
                       const float* __restrict__ x, const float* __restrict__ W1,
                       const float* __restrict__ g1, const float* __restrict__ b1,
                       const float* __restrict__ m1, const float* __restrict__ v1,
                       __half* __restrict__ h, int N, int K, int E, int NB, int CAP) {
    __shared__ unsigned stg[CAPB];
    __shared__ int rcnt[256], rbase[256], rcur[256], sc[256];
    __shared__ float w1s[32 * 16];
    __shared__ float scb[16], bib[16];
    int b = blockIdx.x;
    int r0 = b << 8;
    int nr = N - r0; if (nr > 256) nr = 256;
    int gbeg = bbase[b], gend = bbase[b + 1];
    int count = gend - gbeg;
    size_t tbase = CAP ? (size_t)b * CAP : (size_t)gbeg;
    for (int t = threadIdx.x; t < K * 16; t += 256) w1s[t] = W1[t];
    if (threadIdx.x < 16) {
        float scale = g1[threadIdx.x] * rsqrtf(v1[threadIdx.x] + EPSBN);
        scb[threadIdx.x] = scale;
        bib[threadIdx.x] = b1[threadIdx.x] - m1[threadIdx.x] * scale;
    }
    rcnt[threadIdx.x] = 0;
    __syncthreads();
    for (int i = threadIdx.x; i < count; i += 256)
        atomicAdd(&rcnt[tmp[tbase + i] >> 24], 1);
    __syncthreads();
    int v = rcnt[threadIdx.x];
    sc[threadIdx.x] = v;
    __syncthreads();
    for (int off = 1; off < 256; off <<= 1) {
        int t = (threadIdx.x >= off) ? sc[threadIdx.x - off] : 0;
        __syncthreads();
        sc[threadIdx.x] += t;
        __syncthreads();
    }
    rbase[threadIdx.x] = sc[threadIdx.x] - v;
    rcur[threadIdx.x] = sc[threadIdx.x] - v;
    if (threadIdx.x < nr) offsets[r0 + threadIdx.x] = gbeg + rbase[threadIdx.x];
    if (b == NB - 1 && threadIdx.x == 0) offsets[N] = E;
    __syncthreads();

    if (count <= CAPB) {
        for (int i = threadIdx.x; i < count; i += 256) {
            unsigned vv = tmp[tbase + i];
            int slot = atomicAdd(&rcur[vv >> 24], 1);
            stg[slot] = vv & 0x00FFFFFFu;
        }
        __syncthreads();
        for (int i = threadIdx.x; i < count; i += 256)
            entries[gbeg + i] = stg[i];
        if (threadIdx.x < nr) {
            float acc[16];
#pragma unroll
            for (int c = 0; c < 16; ++c) acc[c] = 0.f;
            int rb = rbase[threadIdx.x], re = rb + rcnt[threadIdx.x];
            for (int i = rb; i < re; ++i) {
                unsigned vv = stg[i];
                float xv = x[vv & 0x7FFFFu];
                const float* wr = &w1s[((vv >> 19) & 31) << 4];
#pragma unroll
                for (int c = 0; c < 16; ++c) acc[c] = fmaf(xv, wr[c], acc[c]);
            }
            int row = r0 + threadIdx.x;
            float4 pack[2];
            __half2* hp = (__half2*)pack;
#pragma unroll
            for (int q = 0; q < 8; ++q) {
                __half2 hh;
                hh.x = __float2half(elu1(acc[2 * q] * scb[2 * q] + bib[2 * q]));
                hh.y = __float2half(elu1(acc[2 * q + 1] * scb[2 * q + 1] + bib[2 * q + 1]));
                hp[q] = hh;
            }
            float4* dst = (float4*)(h + (size_t)row * 16);
            dst[0] = pack[0];
            dst[1] = pack[1];
        }
    } else {
        for (int i = threadIdx.x; i < count; i += 256) {
            unsigned vv = tmp[tbase + i];
            int slot = atomicAdd(&rcur[vv >> 24], 1);
            entries[gbeg + slot] = vv & 0x00FFFFFFu;
        }
        __syncthreads();
        if (threadIdx.x < nr) {
            float acc[16];
#pragma unroll
            for (int c = 0; c < 16; ++c) acc[c] = 0.f;
            int rb = rbase[threadIdx.x], re = rb + rcnt[threadIdx.x];
            for (int i = rb; i < re; ++i) {
                unsigned vv = entries[gbeg + i];
                float xv = x[vv & 0x7FFFFu];
                const float* wr = &w1s[((vv >> 19) & 31) << 4];
#pragma unroll
                for (int c = 0; c < 16; ++c) acc[c] = fmaf(xv, wr[c], acc[c]);
            }
            int row = r0 + threadIdx.x;
            float4 pack[2];
            __half2* hp = (__half2*)pack;
#pragma unroll
            for (int q = 0; q < 8; ++q) {
                __half2 hh;
                hh.x = __float2half(elu1(acc[2 * q] * scb[2 * q] + bib[2 * q]));
                hh.y = __float2half(elu1(acc[2 * q + 1] * scb[2 * q + 1] + bib[2 * q + 1]));
                hp[q] = hh;
            }
            float4* dst = (float4*)(h + (size_t)row * 16);
            dst[0] = pack[0];
            dst[1] = pack[1];
        }
    }
}

// W2T[k][d][c] = (half)W2[k][c][d]  (27 KB, L1-resident)
__global__ void transpose_W2(const float* __restrict__ W2, __half* __restrict__ W2T, int total) {
    int i = blockIdx.x * 256 + threadIdx.x;
    if (i >= total) return;
    int k = i >> 9;
    int r = i & 511;
    int c = r >> 5, d = r & 31;
    W2T[(k << 9) | (d << 4) | c] = __float2half(W2[i]);
}

// ============================================================================
// Stage 2 gather v4: row-pair pipeline. Each half-wave owns 2 rows; both rows'
// cooperative h loads are issued before either compute phase (2x MLP/wave).
// Inner dot loop identical to the proven v2.
// ============================================================================

__global__ void s2_gather_v4(const __half* __restrict__ h, const __half* __restrict__ W2T,
                             const float* __restrict__ g2, const float* __restrict__ b2,
                             const float* __restrict__ m2, const float* __restrict__ v2,
                             const int* __restrict__ offsets, const unsigned* __restrict__ entries,
                             float* __restrict__ out, int N, int shift, unsigned mask) {
    __shared__ __half stg[8][2][32 * 16 + 8];
    int hw = threadIdx.x >> 5;
    int lane = threadIdx.x & 31;
    int row0 = blockIdx.x * 16 + hw * 2;
    if (row0 >= N) return;
    int d = lane;
    int beg[2], end[2], cnt0[2];
    unsigned ev[2];
    float acc[2] = {0.f, 0.f};
#pragma unroll
    for (int r = 0; r < 2; ++r) {
        int row = row0 + r;
        if (row < N) { beg[r] = offsets[row]; end[r] = offsets[row + 1]; }
        else { beg[r] = 0; end[r] = 0; }
        int cnt = end[r] - beg[r]; if (cnt > 32) cnt = 32;
        cnt0[r] = cnt;
        if (cnt > 0) {
            ev[r] = entries[beg[r] + (lane < cnt ? lane : cnt - 1)];
            if (lane < cnt) {
                const float4* hp = (const float4*)(h + ((size_t)(ev[r] & mask) << 4));
                float4 h0 = hp[0], h1 = hp[1];
                float4* dst = (float4*)(&stg[hw][r][lane * 16]);
                dst[0] = h0;
                dst[1] = h1;
            }
        }
    }
    asm volatile("s_waitcnt lgkmcnt(0)" ::: "memory");
#pragma unroll
    for (int r = 0; r < 2; ++r) {
        int row = row0 + r;
        if (row >= N) continue;
        __half* my = stg[hw][r];
        // chunk 0 (preloaded)
        {
            int cnt = cnt0[r];
            int j = 0;
            for (; j + 1 < cnt; j += 2) {
                unsigned pk0 = __shfl(ev[r], j, 32);
                unsigned pk1 = __shfl(ev[r], j + 1, 32);
                const float4* hr0 = (const float4*)(my + j * 16);
                const float4* hr1 = (const float4*)(my + (j + 1) * 16);
                float4 ha0 = hr0[0], hb0 = hr0[1];
                float4 ha1 = hr1[0], hb1 = hr1[1];
                const float4* wp0 = (const float4*)(W2T + (((size_t)(pk0 >> shift) << 9) | ((unsigned)d << 4)));
                const float4* wp1 = (const float4*)(W2T + (((size_t)(pk1 >> shift) << 9) | ((unsigned)d << 4)));
                acc[r] = dot8h(ha0, wp0[0], acc[r]);
                acc[r] = dot8h(hb0, wp0[1], acc[r]);
                acc[r] = dot8h(ha1, wp1[0], acc[r]);
                acc[r] = dot8h(hb1, wp1[1], acc[r]);
            }
            if (j < cnt) {
                unsigned pk0 = __shfl(ev[r], j, 32);
                const float4* hr0 = (const float4*)(my + j * 16);
                float4 ha0 = hr0[0], hb0 = hr0[1];
                const float4* wp0 = (const float4*)(W2T + (((size_t)(pk0 >> shift) << 9) | ((unsigned)d << 4)));
                acc[r] = dot8h(ha0, wp0[0], acc[r]);
                acc[r] = dot8h(hb0, wp0[1], acc[r]);
            }
        }
        // rare extra chunks
        for (int base = beg[r] + 32; base < end[r]; base += 32) {
            int cnt = end[r] - base; if (cnt > 32) cnt = 32;
            unsigned ev2 = entries[base + (lane < cnt ? lane : cnt - 1)];
            asm volatile("s_waitcnt lgkmcnt(0)" ::: "memory");
            if (lane < cnt) {
                const float4* hp = (const float4*)(h + ((size_t)(ev2 & mask) << 4));
                float4 h0 = hp[0], h1 = hp[1];
                float4* dst = (float4*)(my + lane * 16);
                dst[0] = h0;
                dst[1] = h1;
            }
            asm volatile("s_waitcnt lgkmcnt(0)" ::: "memory");
            int j = 0;
            for (; j + 1 < cnt; j += 2) {
                unsigned pk0 = __shfl(ev2, j, 32);
                unsigned pk1 = __shfl(ev2, j + 1, 32);
                const float4* hr0 = (const float4*)(my + j * 16);
                const float4* hr1 = (const float4*)(my + (j + 1) * 16);
                float4 ha0 = hr0[0], hb0 = hr0[1];
                float4 ha1 = hr1[0], hb1 = hr1[1];
                const float4* wp0 = (const float4*)(W2T + (((size_t)(pk0 >> shift) << 9) | ((unsigned)d << 4)));
                const float4* wp1 = (const float4*)(W2T + (((size_t)(pk1 >> shift) << 9) | ((unsigned)d << 4)));
                acc[r] = dot8h(ha0, wp0[0], acc[r]);
                acc[r] = dot8h(hb0, wp0[1], acc[r]);
                acc[r] = dot8h(ha1, wp1[0], acc[r]);
                acc[r] = dot8h(hb1, wp1[1], acc[r]);
            }
            if (j < cnt) {
                unsigned pk0 = __shfl(ev2, j, 32);
                const float4* hr0 = (const float4*)(my + j * 16);
                float4 ha0 = hr0[0], hb0 = hr0[1];
                const float4* wp0 = (const float4*)(W2T + (((size_t)(pk0 >> shift) << 9) | ((unsigned)d << 4)));
                acc[r] = dot8h(ha0, wp0[0], acc[r]);
                acc[r] = dot8h(hb0, wp0[1], acc[r]);
            }
        }
        float scale = g2[d] * rsqrtf(v2[d] + EPSBN);
        float bias = b2[d] - m2[d] * scale;
        out[(size_t)row * 32 + d] = elu1(acc[r] * scale + bias);
    }
}

// v2 retained for the non-radix CSR path
__global__ void s2_gather_v2(const __half* __restrict__ h, const __half* __restrict__ W2T,
                             const float* __restrict__ g2, const float* __restrict__ b2,
                             const float* __restrict__ m2, const float* __restrict__ v2,
                             const int* __restrict__ offsets, const unsigned* __restrict__ entries,
                             float* __restrict__ out, int N, int shift, unsigned mask) {
    __shared__ __half stg[8][32 * 16 + 8];
    int hw = threadIdx.x >> 5;
    int lane = threadIdx.x & 31;
    int row = blockIdx.x * 8 + hw;
    if (row >= N) return;
    int d = lane;
    int beg = offsets[row], end = offsets[row + 1];
    float acc = 0.f;
    __half* my = stg[hw];
    for (int base = beg; base < end; base += 32) {
        int cnt = end - base; if (cnt > 32) cnt = 32;
        unsigned ev = entries[base + (lane < cnt ? lane : cnt - 1)];
        if (lane < cnt) {
            const float4* hp = (const float4*)(h + ((size_t)(ev & mask) << 4));
            float4 h0 = hp[0], h1 = hp[1];
            float4* dst = (float4*)(my + lane * 16);
            dst[0] = h0;
            dst[1] = h1;
        }
        asm volatile("s_waitcnt lgkmcnt(0)" ::: "memory");
        int j = 0;
        for (; j + 1 < cnt; j += 2) {
            unsigned pk0 = __shfl(ev, j, 32);
            unsigned pk1 = __shfl(ev, j + 1, 32);
            const float4* hr0 = (const float4*)(my + j * 16);
            const float4* hr1 = (const float4*)(my + (j + 1) * 16);
            float4 ha0 = hr0[0], hb0 = hr0[1];
            float4 ha1 = hr1[0], hb1 = hr1[1];
            const float4* wp0 = (const float4*)(W2T + (((size_t)(pk0 >> shift) << 9) | ((unsigned)d << 4)));
            const float4* wp1 = (const float4*)(W2T + (((size_t)(pk1 >> shift) << 9) | ((unsigned)d << 4)));
            acc = dot8h(ha0, wp0[0], acc);
            acc = dot8h(hb0, wp0[1], acc);
            acc = dot8h(ha1, wp1[0], acc);
            acc = dot8h(hb1, wp1[1], acc);
        }
        if (j < cnt) {
            unsigned pk0 = __shfl(ev, j, 32);
            const float4* hr0 = (const float4*)(my + j * 16);
            float4 ha0 = hr0[0], hb0 = hr0[1];
            const float4* wp0 = (const float4*)(W2T + (((size_t)(pk0 >> shift) << 9) | ((unsigned)d << 4)));
            acc = dot8h(ha0, wp0[0], acc);
            acc = dot8h(hb0, wp0[1], acc);
        }
        asm volatile("s_waitcnt lgkmcnt(0)" ::: "memory");
    }
    float scale = g2[d] * rsqrtf(v2[d] + EPSBN);
    float bias = b2[d] - m2[d] * scale;
    out[(size_t)row * 32 + d] = elu1(acc * scale + bias);
}

// ============================================================================
// Non-radix CSR fallback kernels
// ============================================================================

__global__ void hist_kernel(const int* __restrict__ out_idx, int* __restrict__ cnt, int M) {
    int m = (blockIdx.x * blockDim.x + threadIdx.x) * 4;
    if (m >= M) return;
    size_t e = (size_t)blockIdx.y * M + m;
    if (m + 3 < M && ((M & 3) == 0)) {
        int4v v = *(const int4v*)(out_idx + e);
        atomicAdd(&cnt[v.x], 1);
        atomicAdd(&cnt[v.y], 1);
        atomicAdd(&cnt[v.z], 1);
        atomicAdd(&cnt[v.w], 1);
    } else {
        for (int j = 0; j < M - m && j < 4; ++j) atomicAdd(&cnt[out_idx[e + j]], 1);
    }
}

__global__ void scan_block_sums(const int* __restrict__ cnt, int* __restrict__ bsum, int N) {
    __shared__ int tmp[256];
    int i = blockIdx.x * 256 + threadIdx.x;
    tmp[threadIdx.x] = (i < N) ? cnt[i] : 0;
    __syncthreads();
    for (int off = 128; off > 0; off >>= 1) {
        if (threadIdx.x < off) tmp[threadIdx.x] += tmp[threadIdx.x + off];
        __syncthreads();
    }
    if (threadIdx.x == 0) bsum[blockIdx.x] = tmp[0];
}

__global__ void scan_bsums(int* __restrict__ bsum, int nb, int* __restrict__ offsets, int N, int E) {
    __shared__ int tmp[256];
    int carry = 0;
    for (int base = 0; base < nb; base += 256) {
        int i = base + threadIdx.x;
        int v = (i < nb) ? bsum[i] : 0;
        tmp[threadIdx.x] = v;
        __syncthreads();
        for (int off = 1; off < 256; off <<= 1) {
            int t = (threadIdx.x >= off) ? tmp[threadIdx.x - off] : 0;
            __syncthreads();
            tmp[threadIdx.x] += t;
            __syncthreads();
        }
        int incl = tmp[threadIdx.x];
        int total = tmp[255];
        if (i < nb) bsum[i] = incl - v + carry;
        carry += total;
        __syncthreads();
    }
    if (threadIdx.x == 0) offsets[N] = E;
}

__global__ void scan_final(const int* __restrict__ cnt, const int* __restrict__ bsum,
                           int* __restrict__ offsets, int* __restrict__ cursor, int N) {
    __shared__ int tmp[256];
    int i = blockIdx.x * 256 + threadIdx.x;
    int v = (i < N) ? cnt[i] : 0;
    tmp[threadIdx.x] = v;
    __syncthreads();
    for (int off = 1; off < 256; off <<= 1) {
        int t = (threadIdx.x >= off) ? tmp[threadIdx.x - off] : 0;
        __syncthreads();
        tmp[threadIdx.x] += t;
        __syncthreads();
    }
    if (i < N) {
        int o = tmp[threadIdx.x] - v + bsum[blockIdx.x];
        offsets[i] = o;
        cursor[i] = o;
    }
}

__global__ void scatter_entries(const int* __restrict__ in_idx, const int* __restrict__ out_idx,
                                int* __restrict__ cursor, unsigned* __restrict__ entries, int M, int shift) {
    int m = blockIdx.x * blockDim.x + threadIdx.x;
    if (m >= M) return;
    int k = blockIdx.y;
    size_t e = (size_t)k * M + m;
    int pos = atomicAdd(&cursor[out_idx[e]], 1);
    entries[pos] = (unsigned)in_idx[e] | ((unsigned)k << shift);
}

__global__ void s1_gather_v2(const float* __restrict__ x, const float* __restrict__ W1,
                             const float* __restrict__ g1, const float* __restrict__ b1,
                             const float* __restrict__ m1, const float* __restrict__ v1,
                             const int* __restrict__ offsets, const unsigned* __restrict__ entries,
                             __half* __restrict__ h, int N, int K, int shift, unsigned mask) {
    __shared__ float w1s[32 * 16];
    for (int t = threadIdx.x; t < K * 16 && t < 512; t += 256) w1s[t] = W1[t];
    __syncthreads();
    int row = blockIdx.x * 16 + (threadIdx.x >> 4);
    int c = threadIdx.x & 15;
    if (row >= N) return;
    int beg = offsets[row], end = offsets[row + 1];
    float acc = 0.f;
    for (int base = beg; base < end; base += 16) {
        int cnt = end - base; if (cnt > 16) cnt = 16;
        unsigned ev = entries[base + (c < cnt ? c : cnt - 1)];
        float xv = x[ev & mask];
        for (int j = 0; j < cnt; ++j) {
            unsigned pk = __shfl(ev, j, 16);
            float xj = __shfl(xv, j, 16);
            acc = fmaf(xj, w1s[(int)((pk >> shift) << 4) | c], acc);
        }
    }
    float scale = g1[c] * rsqrtf(v1[c] + EPSBN);
    float bias = b1[c] - m1[c] * scale;
    h[(size_t)row * 16 + c] = __float2half(elu1(acc * scale + bias));
}

// ============================================================================
// Last-resort fallback: atomic path (fp32 throughout)
// ============================================================================

__global__ void s1_scatter_slab(const float* __restrict__ x, const int* __restrict__ in_idx,
                                const int* __restrict__ out_idx, float* __restrict__ s, int M, int N) {
    int m = blockIdx.x * blockDim.x + threadIdx.x;
    if (m >= M) return;
    int k = blockIdx.y;
    size_t e = (size_t)k * M + m;
    unsafeAtomicAdd(&s[(size_t)k * N + out_idx[e]], x[in_idx[e]]);
}

__global__ void s1_combine(const float* __restrict__ s, const float* __restrict__ W1,
                           const float* __restrict__ g1, const float* __restrict__ b1,
                           const float* __restrict__ m1, const float* __restrict__ v1,
                           float* __restrict__ h, int N, int K) {
    __shared__ float w[32 * 16];
    __shared__ float sc[16], bi[16];
    for (int t = threadIdx.x; t < K * 16; t += blockDim.x) w[t] = W1[t];
    if (threadIdx.x < 16) {
        float scale = g1[threadIdx.x] * rsqrtf(v1[threadIdx.x] + EPSBN);
        sc[threadIdx.x] = scale;
        bi[threadIdx.x] = b1[threadIdx.x] - m1[threadIdx.x] * scale;
    }
    __syncthreads();
    int n = blockIdx.x * blockDim.x + threadIdx.x;
    if (n >= N) return;
    float acc[16];
#pragma unroll
    for (int c = 0; c < 16; ++c) acc[c] = 0.f;
    for (int k = 0; k < K; ++k) {
        float sv = s[(size_t)k * N + n];
#pragma unroll
        for (int c = 0; c < 16; ++c) acc[c] = fmaf(sv, w[k * 16 + c], acc[c]);
    }
    float4* hv = (float4*)(h + (size_t)n * 16);
#pragma unroll
    for (int q = 0; q < 4; ++q) {
        float4 o;
        o.x = elu1(acc[q * 4 + 0] * sc[q * 4 + 0] + bi[q * 4 + 0]);
        o.y = elu1(acc[q * 4 + 1] * sc[q * 4 + 1] + bi[q * 4 + 1]);
        o.z = elu1(acc[q * 4 + 2] * sc[q * 4 + 2] + bi[q * 4 + 2]);
        o.w = elu1(acc[q * 4 + 3] * sc[q * 4 + 3] + bi[q * 4 + 3]);
        hv[q] = o;
    }
}

__global__ void bn_elu_c(float* __restrict__ buf, const float* __restrict__ g,
                         const float* __restrict__ b, const float* __restrict__ m,
                         const float* __restrict__ v, size_t total, int cmask) {
    size_t i = (size_t)blockIdx.x * blockDim.x + threadIdx.x;
    if (i >= total) return;
    int c = (int)(i & (size_t)cmask);
    float scale = g[c] * rsqrtf(v[c] + EPSBN);
    buf[i] = elu1((buf[i] - m[c]) * scale + b[c]);
}

__global__ void s2_scatter(const float* __restrict__ h, const float* __restrict__ W2,
                           const int* __restrict__ in_idx, const int* __restrict__ out_idx,
                           float* __restrict__ acc, int M) {
    __shared__ float w[16 * 32];
    int k = blockIdx.y;
    for (int t = threadIdx.x; t < 512; t += blockDim.x) w[t] = W2[(size_t)k * 512 + t];
    __syncthreads();
    int m = blockIdx.x * blockDim.x + threadIdx.x;
    if (m >= M) return;
    size_t e = (size_t)k * M + m;
    int in = in_idx[e], out = out_idx[e];
    const float4* hr = (const float4*)(h + (size_t)in * 16);
    float4 h0 = hr[0], h1 = hr[1], h2 = hr[2], h3 = hr[3];
    float hrow[16] = {h0.x, h0.y, h0.z, h0.w, h1.x, h1.y, h1.z, h1.w,
                      h2.x, h2.y, h2.z, h2.w, h3.x, h3.y, h3.z, h3.w};
    float yv[32];
#pragma unroll
    for (int dd = 0; dd < 32; ++dd) yv[dd] = 0.f;
#pragma unroll
    for (int c = 0; c < 16; ++c) {
        float hv = hrow[c];
#pragma unroll
        for (int dd = 0; dd < 32; ++dd) yv[dd] = fmaf(hv, w[c * 32 + dd], yv[dd]);
    }
    float* ar = acc + (size_t)out * 32;
#pragma unroll
    for (int dd = 0; dd < 32; ++dd) unsafeAtomicAdd(&ar[dd], yv[dd]);
}

// ============================================================================

extern "C" void kernel_launch(void* const* d_in, const int* in_sizes, int n_in,
                              void* d_out, int out_size, void* d_ws, size_t ws_size,
                              hipStream_t stream) {
    const float* x  = (const float*)d_in[0];
    const float* W1 = (const float*)d_in[1];
    const float* g1 = (const float*)d_in[2];
    const float* b1 = (const float*)d_in[3];
    const float* m1 = (const float*)d_in[4];
    const float* v1 = (const float*)d_in[5];
    const float* W2 = (const float*)d_in[6];
    const float* g2 = (const float*)d_in[7];
    const float* b2 = (const float*)d_in[8];
    const float* m2 = (const float*)d_in[9];
    const float* v2 = (const float*)d_in[10];
    const int* in_idx  = (const int*)d_in[11];
    const int* out_idx = (const int*)d_in[12];

    const int N  = in_sizes[0];
    const int C1 = in_sizes[2];           // 16
    const int K  = in_sizes[1] / C1;      // 27
    const int M  = in_sizes[11] / K;      // 200000
    const int E  = K * M;                 // 5.4M
    const int nb = (N + 255) / 256;
    const int NB = (N + 255) >> 8;        // radix buckets (256 rows each)

    float* out = (float*)d_out;
    dim3 blk(256);
    dim3 grdKM((M + 255) / 256, K);

    auto align256 = [](size_t v) { return (v + 255) & ~(size_t)255; };

    // ---- common sizes ----
    size_t bbaseB = align256((size_t)(NB + 1) * 4);
    size_t bcurB  = align256((size_t)NB * 16 * 4);
    size_t entB   = align256((size_t)E * 4);
    size_t offB   = align256((size_t)(N + 1) * 4);
    size_t w2tB   = align256((size_t)K * 512 * 2);
    size_t hB     = align256((size_t)N * 16 * 2);

    bool radixOK = (N <= (1 << 19)) && (K <= 32) && (NB <= NBMAX);

    // ---- slab-radix path (no pre-histogram) ----
    double avgc = (double)E / (double)(NB > 0 ? NB : 1);
    int CAP = (int)(avgc + 6.0 * sqrt(avgc) + 64.0);
    CAP = (CAP + 63) & ~63;
    size_t slabB = align256((size_t)NB * (size_t)CAP * 4);
    size_t slabNeed = bbaseB + bcurB + slabB + entB + offB + w2tB + hB;

    if (radixOK && ws_size >= slabNeed) {
        char* p = (char*)d_ws;
        int* bbase      = (int*)p;            p += bbaseB;
        int* bcur       = (int*)p;            p += bcurB;
        unsigned* tmp   = (unsigned*)p;       p += slabB;
        unsigned* ent   = (unsigned*)p;       p += entB;
        int* offsets    = (int*)p;            p += offB;
        __half* W2T     = (__half*)p;         p += w2tB;
        __half* h       = (__half*)p;

        init_slab<<<dim3((NB + 255) / 256), blk, 0, stream>>>(bcur, NB, CAP);
        transpose_W2<<<dim3((K * 512 + 255) / 256), blk, 0, stream>>>(W2, W2T, K * 512);
        passA<<<dim3((M + 256 * TPT - 1) / (256 * TPT), K), blk, 0, stream>>>(in_idx, out_idx, bcur, tmp, M, NB);
        bscan2<<<dim3(1), blk, 0, stream>>>(bcur, bbase, NB, E, CAP);
        passB2<<<dim3(NB), blk, 0, stream>>>(tmp, bbase, ent, offsets, x, W1, g1, b1, m1, v1, h, N, K, E, NB, CAP);
        s2_gather_v4<<<dim3((N + 15) / 16), blk, 0, stream>>>(h, W2T, g2, b2, m2, v2, offsets, ent, out, N, 19, 0x7FFFFu);
        return;
    }

    // ---- bhist-radix path (round-14 proven) ----
    size_t bcntB = align256((size_t)NB * 4);
    size_t tmpB  = align256((size_t)E * 4);
    size_t radixNeed = bcntB + bbaseB + bcurB + tmpB + entB + offB + w2tB + hB;

    if (radixOK && ws_size >= radixNeed) {
        char* p = (char*)d_ws;
        int* bcnt       = (int*)p;            p += bcntB;
        int* bbase      = (int*)p;            p += bbaseB;
        int* bcur       = (int*)p;            p += bcurB;
        unsigned* tmp   = (unsigned*)p;       p += tmpB;
        unsigned* ent   = (unsigned*)p;       p += entB;
        int* offsets    = (int*)p;            p += offB;
        __half* W2T     = (__half*)p;         p += w2tB;
        __half* h       = (__half*)p;

        hipMemsetAsync(bcnt, 0, (size_t)NB * 4, stream);
        bhist_lds<<<dim3((M + 256 * TPT - 1) / (256 * TPT), K), blk, 0, stream>>>(out_idx, bcnt, M, NB);
        transpose_W2<<<dim3((K * 512 + 255) / 256), blk, 0, stream>>>(W2, W2T, K * 512);
        bscan<<<dim3(1), blk, 0, stream>>>(bcnt, bbase, bcur, NB, E);
        passA<<<dim3((M + 256 * TPT - 1) / (256 * TPT), K), blk, 0, stream>>>(in_idx, out_idx, bcur, tmp, M, NB);
        passB2<<<dim3(NB), blk, 0, stream>>>(tmp, bbase, ent, offsets, x, W1, g1, b1, m1, v1, h, N, K, E, NB, 0);
        s2_gather_v4<<<dim3((N + 15) / 16), blk, 0, stream>>>(h, W2T, g2, b2, m2, v2, offsets, ent, out, N, 19, 0x7FFFFu);
        return;
    }

    // ---- non-radix CSR layout ----
    size_t cntB   = align256((size_t)N * 4);
    size_t bsumB  = align256((size_t)nb * 4);
    size_t curB   = align256((size_t)N * 4);
    size_t csrNeed = cntB + offB + bsumB + entB + w2tB + hB + curB;
    bool canCSR = (N < (1 << 24)) && (K < 256) && (ws_size >= csrNeed);

    if (canCSR) {
        char* p = (char*)d_ws;
        int* cnt        = (int*)p;            p += cntB;
        int* offsets    = (int*)p;            p += offB;
        int* bsum       = (int*)p;            p += bsumB;
        unsigned* ent   = (unsigned*)p;       p += entB;
        __half* W2T     = (__half*)p;         p += w2tB;
        __half* h       = (__half*)p;         p += hB;
        int* cursor     = (int*)p;

        hipMemsetAsync(cnt, 0, (size_t)N * 4, stream);
        hist_kernel<<<dim3((M / 4 + 256) / 256, K), blk, 0, stream>>>(out_idx, cnt, M);
        transpose_W2<<<dim3((K * 512 + 255) / 256), blk, 0, stream>>>(W2, W2T, K * 512);
        scan_block_sums<<<dim3(nb), blk, 0, stream>>>(cnt, bsum, N);
        scan_bsums<<<dim3(1), blk, 0, stream>>>(bsum, nb, offsets, N, E);
        scan_final<<<dim3(nb), blk, 0, stream>>>(cnt, bsum, offsets, cursor, N);
        scatter_entries<<<grdKM, blk, 0, stream>>>(in_idx, out_idx, cursor, ent, M, 24);
        s1_gather_v2<<<dim3((N + 15) / 16), blk, 0, stream>>>(x, W1, g1, b1, m1, v1, offsets, ent, h, N, K, 24, 0xFFFFFFu);
        s2_gather_v2<<<dim3((N + 7) / 8), blk, 0, stream>>>(h, W2T, g2, b2, m2, v2, offsets, ent, out, N, 24, 0xFFFFFFu);
        return;
    }

    // ---- last-resort atomic path ----
    size_t sBytes = align256((size_t)K * N * 4);
    size_t hBytes = (size_t)N * 16 * 4;
    float* hf = (float*)d_ws;
    if (ws_size >= sBytes + hBytes) {
        float* s = (float*)d_ws;
        hf = (float*)((char*)d_ws + sBytes);
        hipMemsetAsync(s, 0, (size_t)K * N * 4, stream);
        s1_scatter_slab<<<grdKM, blk, 0, stream>>>(x, in_idx, out_idx, s, M, N);
        s1_combine<<<dim3((N + 255) / 256), blk, 0, stream>>>(s, W1, g1, b1, m1, v1, hf, N, K);
    }
    hipMemsetAsync(out, 0, (size_t)N * 32 * 4, stream);
    s2_scatter<<<grdKM, blk, 0, stream>>>(hf, W2, in_idx, out_idx, out, M);
    size_t tot2 = (size_t)N * 32;
    bn_elu_c<<<dim3((unsigned)((tot2 + 255) / 256)), blk, 0, stream>>>(out, g2, b2, m2, v2, tot2, 31);
}